// Round 2
// baseline (1072.340 us; speedup 1.0000x reference)
//
#include <hip/hip_runtime.h>
#include <hip/hip_cooperative_groups.h>
#include <math.h>

namespace cg = cooperative_groups;

// ---------------------------------------------------------------------------
// B=16, NP1=65, BT=1040, Mg=256, D=512, H=8, DH=64, L=3, DFF=2048
// R10: single cooperative megakernel. R9's dbuf GEMM change was exactly
// neutral (-0.2%), falsifying "GEMM interiors dominate". Cycle-level floors
// put real GPU work at ~100-150us of the 406us => ~250us is inter-dispatch
// overhead across 24 serially-dependent graph nodes. This folds all stages
// into one kernel with 23 grid.sync()s, reusing a 52KB LDS union.
// ---------------------------------------------------------------------------

#define BT   1040
#define NP1  65
#define Dm   512
#define MG   256

typedef short short8 __attribute__((ext_vector_type(8)));
typedef float f32x4  __attribute__((ext_vector_type(4)));
typedef unsigned short u16;

__device__ __forceinline__ u16 f2bf(float f) {
  unsigned int u = __float_as_uint(f);
  u += 0x7FFF + ((u >> 16) & 1);          // RNE
  return (u16)(u >> 16);
}

__device__ __forceinline__ float gelu_exact(float x) {
  return 0.5f * x * (1.0f + erff(x * 0.70710678118654752f));
}

__device__ __forceinline__ void async16(const u16* g, u16* l) {
  __builtin_amdgcn_global_load_lds(
      (const __attribute__((address_space(1))) unsigned int*)g,
      (__attribute__((address_space(3))) unsigned int*)l, 16, 0, 0);
}

__device__ __forceinline__ float wred(float v) {
#pragma unroll
  for (int o = 32; o; o >>= 1) v += __shfl_xor(v, o, 64);
  return v;
}

__device__ __forceinline__ float block_reduce_sum(float v, float* s) {
#pragma unroll
  for (int off = 32; off; off >>= 1) v += __shfl_down(v, off, 64);
  int lane = threadIdx.x & 63, wid = threadIdx.x >> 6;
  __syncthreads();
  if (lane == 0) s[wid] = v;
  __syncthreads();
  return s[0] + s[1] + s[2] + s[3];
}

// closed-form expected grid value under weights exp(-a*x_j/eps), x_j uniform:
__device__ __forceinline__ float f_closed(float a) {
  const float tf = 2.3529411765f;     // (6/255)*100
  float t = a * tf;
  float s = fabsf(t);
  float E;
  if (s < 1e-4f) {
    E = 127.5f - 5461.25f * t;        // series; kappa2=(256^2-1)/12
  } else {
    float u = s * 256.0f;
    float term2 = (u < 80.0f) ? 256.0f / expm1f(u) : 0.0f;
    float Epos = 1.0f / expm1f(s) - term2;
    E = (t > 0.0f) ? Epos : 255.0f - Epos;
  }
  return -3.0f + 0.0235294118f * E;   // delta = 6/255
}

struct MegaArgs {
  const float *marg, *xg, *conv_w, *conv_b, *fc_w, *fc_b, *ln0_g, *ln0_b, *pos;
  const float *qkv_b, *out_b, *ln1_g, *ln1_b, *ff1_b, *ff2_b, *ln2_g, *ln2_b;
  const float *u_b, *h_b;
  const float *qkv_w, *out_w, *ff1_w, *ff2_w, *u_w, *h_w;
  float *out, *xs, *qkvbuf, *part, *hbuf;
  u16 *xsb, *obufb, *ffb, *wbf;
};

// ---------------------------------------------------------------------------
// stage helpers (all called under uniform control flow per block)
// ---------------------------------------------------------------------------

__device__ __forceinline__ void convert_weights(
    int bid, int half, const MegaArgs& a)
{
  const size_t O1 = 2359296, O2 = 3145728, O3 = 6291456;
  const size_t O4 = 9437184, O5 = 9568256, TOT4 = 9699328 / 4;
  for (size_t e4 = (size_t)bid * 256 + threadIdx.x; e4 < TOT4;
       e4 += (size_t)half * 256) {
    size_t e = e4 * 4;
    const float* src;
    if      (e < O1) src = a.qkv_w + e;
    else if (e < O2) src = a.out_w + (e - O1);
    else if (e < O3) src = a.ff1_w + (e - O2);
    else if (e < O4) src = a.ff2_w + (e - O3);
    else if (e < O5) src = a.u_w   + (e - O4);
    else             src = a.h_w   + (e - O5);
    float4 v = *(const float4*)src;
    unsigned int lo = (unsigned int)f2bf(v.x) | ((unsigned int)f2bf(v.y) << 16);
    unsigned int hi = (unsigned int)f2bf(v.z) | ((unsigned int)f2bf(v.w) << 16);
    *(uint2*)(a.wbf + e) = make_uint2(lo, hi);
  }
}

__device__ __forceinline__ void embed_job(int j, const MegaArgs& a, float* smem)
{
  float* es   = smem;            // [4][128]
  float* sS   = smem + 512;      // [4]
  float* edge = smem + 516;      // [4][4]
  float* red  = smem + 532;      // [4]
  const int tid = threadIdx.x, lane = tid & 63, wave = tid >> 6;
  const int t0 = j * 4;
  __syncthreads();               // LDS reuse guard
  {
    float4 mv = *(const float4*)(a.marg + (size_t)(t0 + wave) * MG + lane * 4);
    float S = wred(mv.x + mv.y + mv.z + mv.w);
    if (lane == 0) sS[wave] = S;
  }
  if (tid < 16) {
    int k = tid >> 2, e = tid & 3;
    int idx = (e < 2) ? e : (e + 252);       // 0,1,254,255
    edge[k * 4 + e] = a.marg[(size_t)(t0 + k) * MG + idx];
  }
  __syncthreads();
  if (tid < 128) {
    int o = tid;
    float w0 = a.conv_w[o*5+0], w1 = a.conv_w[o*5+1], w2 = a.conv_w[o*5+2];
    float w3 = a.conv_w[o*5+3], w4 = a.conv_w[o*5+4], cb = a.conv_b[o];
#pragma unroll
    for (int k = 0; k < 4; ++k) {
      float S = sS[k];
      float x0 = edge[k*4+0], x1 = edge[k*4+1], x254 = edge[k*4+2], x255 = edge[k*4+3];
      es[k*128 + o] = (w0*(S - x254 - x255) + w1*(S - x255) + w2*S
                     + w3*(S - x0) + w4*(S - x0 - x1)) * (1.0f/256.0f) + cb;
    }
  }
  __syncthreads();
  float b0 = a.fc_b[tid], b1 = a.fc_b[tid + 256];
  float z[4][2];
#pragma unroll
  for (int k = 0; k < 4; ++k) { z[k][0] = b0; z[k][1] = b1; }
#pragma unroll 4
  for (int o = 0; o < 128; ++o) {
    float f0 = a.fc_w[(size_t)o*Dm + tid];
    float f1 = a.fc_w[(size_t)o*Dm + tid + 256];
#pragma unroll
    for (int k = 0; k < 4; ++k) {
      float e = es[k*128 + o];
      z[k][0] += e * f0; z[k][1] += e * f1;
    }
  }
  float g0 = a.ln0_g[tid], g1 = a.ln0_g[tid+256];
  float e0 = a.ln0_b[tid], e1 = a.ln0_b[tid+256];
#pragma unroll
  for (int k = 0; k < 4; ++k) {
    float mu = block_reduce_sum(z[k][0] + z[k][1], red) * (1.0f/512.0f);
    float d0 = z[k][0] - mu, d1 = z[k][1] - mu;
    float var = block_reduce_sum(d0*d0 + d1*d1, red) * (1.0f/512.0f);
    float inv = rsqrtf(var + 1e-5f);
    int t = t0 + k, p = t % NP1;
    float y0 = gelu_exact(d0*inv*g0 + e0) + a.pos[(size_t)p*Dm + tid];
    float y1 = gelu_exact(d1*inv*g1 + e1) + a.pos[(size_t)p*Dm + tid + 256];
    a.xs[(size_t)t*Dm + tid]        = y0;
    a.xs[(size_t)t*Dm + tid + 256]  = y1;
    a.xsb[(size_t)t*Dm + tid]       = f2bf(y0);
    a.xsb[(size_t)t*Dm + tid + 256] = f2bf(y1);
  }
}

// 64x64 MFMA tile GEMM, BK=64, async16 dbuf staging, 4 waves 2x2.
// MODE: 0 fp32 v+bias | 1 bf16 gelu(v+bias) | 2 fp32 partial (split-K) | 3 u/h
template<int SPLITS, int MODE>
__device__ __forceinline__ void gemm_tile(
    const u16* __restrict__ A, const u16* __restrict__ Bw,
    const float* __restrict__ bias, float* __restrict__ Cf,
    u16* __restrict__ Cb, float* __restrict__ C2,
    const float* __restrict__ bias2, int Mrows, int N, int K,
    int bx, int by, int bz, u16* Asl, u16* Bsl)
{
  const int tid = threadIdx.x;
  const int row0 = by * 64, col0 = bx * 64;
  const int Ks = K / SPLITS, kbase = bz * Ks;
  const int lane = tid & 63, wave = tid >> 6;
  const int wm = (wave >> 1) * 32, wn = (wave & 1) * 32;
  const int l15 = lane & 15, q = lane >> 4;

  __syncthreads();               // LDS reuse guard (prev stage/job reads done)

  f32x4 acc[2][2];
  acc[0][0] = (f32x4){0,0,0,0}; acc[0][1] = (f32x4){0,0,0,0};
  acc[1][0] = (f32x4){0,0,0,0}; acc[1][1] = (f32x4){0,0,0,0};

  const int arow = min(row0 + lane, Mrows - 1);
  const size_t abase = (size_t)arow * K;
  const size_t bbase = (size_t)(col0 + lane) * K;
  const int c0w = wave * 2;

  // prologue: stage buf0
#pragma unroll
  for (int i = 0; i < 2; ++i) {
    int c = c0w + i;
    async16(A + abase + kbase + c * 8, Asl + (size_t)(c * 64 + lane) * 8);
    async16(Bw + bbase + kbase + c * 8, Bsl + (size_t)(c * 64 + lane) * 8);
  }

  const int nk = Ks >> 6;
  for (int t = 0; t < nk; ++t) {
    const int cur = t & 1;
    if (t + 1 < nk) {
      const int nxt = cur ^ 1;
      const int kk = kbase + (t + 1) * 64;
#pragma unroll
      for (int i = 0; i < 2; ++i) {
        int c = c0w + i;
        async16(A + abase + kk + c * 8, Asl + nxt*4096 + (size_t)(c*64 + lane)*8);
        async16(Bw + bbase + kk + c * 8, Bsl + nxt*4096 + (size_t)(c*64 + lane)*8);
      }
      asm volatile("s_waitcnt vmcnt(4)" ::: "memory");
    } else {
      asm volatile("s_waitcnt vmcnt(0)" ::: "memory");
    }
    __builtin_amdgcn_s_barrier();
#pragma unroll
    for (int tt = 0; tt < 2; ++tt) {
      int cc = tt * 4 + q;
      short8 af[2], bf[2];
#pragma unroll
      for (int mi = 0; mi < 2; ++mi)
        af[mi] = *(short8*)(Asl + cur*4096 + (size_t)(cc*64 + wm + mi*16 + l15) * 8);
#pragma unroll
      for (int ni = 0; ni < 2; ++ni)
        bf[ni] = *(short8*)(Bsl + cur*4096 + (size_t)(cc*64 + wn + ni*16 + l15) * 8);
#pragma unroll
      for (int mi = 0; mi < 2; ++mi)
#pragma unroll
        for (int ni = 0; ni < 2; ++ni)
          acc[mi][ni] = __builtin_amdgcn_mfma_f32_16x16x32_bf16(
              af[mi], bf[ni], acc[mi][ni], 0, 0, 0);
    }
    __builtin_amdgcn_s_barrier();
  }

  float* Cp = Cf;
  if (MODE == 2) Cp += (size_t)bz * (size_t)Mrows * N;
#pragma unroll
  for (int mi = 0; mi < 2; ++mi) {
#pragma unroll
    for (int ni = 0; ni < 2; ++ni) {
      int col = col0 + wn + ni*16 + l15;
#pragma unroll
      for (int r = 0; r < 4; ++r) {
        int row = row0 + wm + mi*16 + q*4 + r;
        if (row < Mrows) {
          float v = acc[mi][ni][r];
          if (MODE == 0) {
            Cp[(size_t)row*N + col] = v + bias[col];
          } else if (MODE == 1) {
            Cb[(size_t)row*N + col] = f2bf(gelu_exact(v + bias[col]));
          } else if (MODE == 2) {
            Cp[(size_t)row*N + col] = v;
          } else {
            if (col < 256) Cf[(size_t)row*256 + col]         = v + bias[col];
            else           C2[(size_t)row*256 + (col - 256)] = v + bias2[col - 256];
          }
        }
      }
    }
  }
}

__device__ __forceinline__ void attn_job(int jj, const float* __restrict__ qkv,
                                         u16* __restrict__ obufb, float* smem)
{
  float (*qv)[67] = (float (*)[67])smem;
  float (*ks)[67] = (float (*)[67])(smem + 4355);
  float (*ss)[67] = (float (*)[67])(smem + 8710);
  const int b = jj >> 3, h = jj & 7;
  const int tid = threadIdx.x;
  const float* base = qkv + (size_t)b * NP1 * 1536 + h * 64;
  __syncthreads();               // LDS reuse guard
  for (int idx = tid; idx < NP1 * 16; idx += 256) {
    int t = idx >> 4, c = (idx & 15) << 2;
    const float* p = base + (size_t)t * 1536 + c;
    float4 q4 = *(const float4*)(p);
    float4 k4 = *(const float4*)(p + 512);
    qv[t][c] = q4.x; qv[t][c+1] = q4.y; qv[t][c+2] = q4.z; qv[t][c+3] = q4.w;
    ks[t][c] = k4.x; ks[t][c+1] = k4.y; ks[t][c+2] = k4.z; ks[t][c+3] = k4.w;
  }
  __syncthreads();
#pragma unroll
  for (int it = 0; it < 2; ++it) {
    int tile = it * 256 + tid;
    if (tile < 289) {
      int ti = (tile / 17) * 4, tj = (tile % 17) * 4;
      const float* qr[4]; const float* kr[4];
#pragma unroll
      for (int i = 0; i < 4; ++i) { qr[i] = qv[min(ti + i, 64)]; kr[i] = ks[min(tj + i, 64)]; }
      float acc[4][4] = {};
      for (int d = 0; d < 64; ++d) {
        float aa[4], bvv[4];
#pragma unroll
        for (int i = 0; i < 4; ++i) { aa[i] = qr[i][d]; bvv[i] = kr[i][d]; }
#pragma unroll
        for (int i = 0; i < 4; ++i)
#pragma unroll
          for (int j = 0; j < 4; ++j) acc[i][j] += aa[i] * bvv[j];
      }
#pragma unroll
      for (int i = 0; i < 4; ++i)
        if (ti + i < 65)
#pragma unroll
          for (int j = 0; j < 4; ++j)
            if (tj + j < 65) ss[ti + i][tj + j] = acc[i][j] * 0.125f;
    }
  }
  __syncthreads();
  for (int idx = tid; idx < NP1 * 16; idx += 256) {
    int t = idx >> 4, c = (idx & 15) << 2;
    float4 v4 = *(const float4*)(base + (size_t)t * 1536 + 1024 + c);
    qv[t][c] = v4.x; qv[t][c+1] = v4.y; qv[t][c+2] = v4.z; qv[t][c+3] = v4.w;
  }
  if (tid < 65) {
    float mx = -1e30f;
    for (int j = 0; j < 65; ++j) mx = fmaxf(mx, ss[tid][j]);
    float s = 0.0f;
    for (int j = 0; j < 65; ++j) { float e = expf(ss[tid][j] - mx); ss[tid][j] = e; s += e; }
    float inv = 1.0f / s;
    for (int j = 0; j < 65; ++j) ss[tid][j] *= inv;
  }
  __syncthreads();
#pragma unroll
  for (int it = 0; it < 2; ++it) {
    int tile = it * 256 + tid;
    if (tile < 272) {
      int ti = (tile >> 4) * 4, d0 = (tile & 15) * 4;
      const float* sr[4];
#pragma unroll
      for (int i = 0; i < 4; ++i) sr[i] = ss[min(ti + i, 64)];
      float acc[4][4] = {};
      for (int j = 0; j < 65; ++j) {
        float v0 = qv[j][d0], v1 = qv[j][d0+1], v2 = qv[j][d0+2], v3 = qv[j][d0+3];
#pragma unroll
        for (int i = 0; i < 4; ++i) {
          float s = sr[i][j];
          acc[i][0] += s * v0; acc[i][1] += s * v1;
          acc[i][2] += s * v2; acc[i][3] += s * v3;
        }
      }
#pragma unroll
      for (int i = 0; i < 4; ++i)
        if (ti + i < 65) {
          ushort4 o;
          o.x = f2bf(acc[i][0]); o.y = f2bf(acc[i][1]);
          o.z = f2bf(acc[i][2]); o.w = f2bf(acc[i][3]);
          *(ushort4*)(obufb + (size_t)(b * NP1 + ti + i) * Dm + h * 64 + d0) = o;
        }
    }
  }
}

template<int S>
__device__ __forceinline__ void addln_job(int j, float* __restrict__ xs,
    u16* __restrict__ xsb, const float* __restrict__ part,
    const float* __restrict__ bias, const float* __restrict__ g,
    const float* __restrict__ bb)
{
  const int lane = threadIdx.x & 63, wave = threadIdx.x >> 6;
  const int t = j * 4 + wave;
  const int c0 = lane * 8;
  float* xp = xs + (size_t)t * Dm;
  float v[8];
  {
    float4 a0 = *(const float4*)(xp + c0), a1 = *(const float4*)(xp + c0 + 4);
    float4 b0 = *(const float4*)(bias + c0), b1 = *(const float4*)(bias + c0 + 4);
    v[0]=a0.x+b0.x; v[1]=a0.y+b0.y; v[2]=a0.z+b0.z; v[3]=a0.w+b0.w;
    v[4]=a1.x+b1.x; v[5]=a1.y+b1.y; v[6]=a1.z+b1.z; v[7]=a1.w+b1.w;
  }
#pragma unroll
  for (int s = 0; s < S; ++s) {
    const float* pp = part + (size_t)s*BT*Dm + (size_t)t*Dm + c0;
    float4 q0 = *(const float4*)pp, q1 = *(const float4*)(pp + 4);
    v[0]+=q0.x; v[1]+=q0.y; v[2]+=q0.z; v[3]+=q0.w;
    v[4]+=q1.x; v[5]+=q1.y; v[6]+=q1.z; v[7]+=q1.w;
  }
  float s1 = 0.f;
#pragma unroll
  for (int jj = 0; jj < 8; ++jj) s1 += v[jj];
  float mu = wred(s1) * (1.0f/512.0f);
  float s2 = 0.f;
#pragma unroll
  for (int jj = 0; jj < 8; ++jj) { float d = v[jj]-mu; s2 += d*d; }
  float inv = rsqrtf(wred(s2) * (1.0f/512.0f) + 1e-5f);
  float4 g0 = *(const float4*)(g + c0), g1 = *(const float4*)(g + c0 + 4);
  float4 e0 = *(const float4*)(bb + c0), e1 = *(const float4*)(bb + c0 + 4);
  float gg[8] = {g0.x,g0.y,g0.z,g0.w,g1.x,g1.y,g1.z,g1.w};
  float ee[8] = {e0.x,e0.y,e0.z,e0.w,e1.x,e1.y,e1.z,e1.w};
  float y[8]; u16 yb[8];
#pragma unroll
  for (int jj = 0; jj < 8; ++jj) { y[jj] = (v[jj]-mu)*inv*gg[jj] + ee[jj]; yb[jj] = f2bf(y[jj]); }
  *(float4*)(xp + c0)     = make_float4(y[0],y[1],y[2],y[3]);
  *(float4*)(xp + c0 + 4) = make_float4(y[4],y[5],y[6],y[7]);
  *(short8*)(xsb + (size_t)t*Dm + c0) = *(short8*)yb;
}

__device__ __forceinline__ void proj_job(int j, const float* __restrict__ hbuf,
    const float* __restrict__ marg, const float* __restrict__ xg,
    float* __restrict__ out_h)
{
  const int tid = threadIdx.x, lane = tid & 63, wave = tid >> 6;
  const int rr = j * 4 + wave;                  // 0..1023
  const int b = rr >> 6, n = rr & 63;
  const int row = b * NP1 + n;
  const int i0 = lane * 4;
  float4 a4 = *(const float4*)(hbuf + (size_t)row * MG + i0);
  float4 x4 = *(const float4*)(xg + i0);
  float4 m4 = *(const float4*)(marg + (size_t)row * MG + i0);
  float av[4] = {a4.x, a4.y, a4.z, a4.w};
  float xv[4] = {x4.x, x4.y, x4.z, x4.w};
  float uv[4] = {m4.x, m4.y, m4.z, m4.w};
  float wd = 0.f, ms = 0.f;
#pragma unroll
  for (int k = 0; k < 4; ++k) {
    float drift = f_closed(av[k]) - xv[k];
    wd += uv[k] * drift; ms += uv[k];
  }
  wd = wred(wd); ms = wred(ms);
  float corr = wd / (ms + 1e-8f);
  *(float4*)(out_h + ((size_t)(b * 64 + n)) * MG + i0) =
      make_float4(av[0]-corr, av[1]-corr, av[2]-corr, av[3]-corr);
}

// ---------------------------------------------------------------------------
// the megakernel
// ---------------------------------------------------------------------------
__global__ __launch_bounds__(256, 2) void mega(MegaArgs a)
{
  cg::grid_group grid = cg::this_grid();
  __shared__ alignas(16) float smem[13072];     // 52.3 KB union: attn 3x65x67,
                                                // gemm 2x(2x4096 u16), embed
  const int bid = blockIdx.x;
  const int nb  = gridDim.x;
  u16* Asl = (u16*)smem;          // 8192 u16 (2 bufs x 4096)
  u16* Bsl = (u16*)smem + 8192;   // 8192 u16

  // ---- stage 0: weight conversion (first half) || embed (second half) ----
  {
    int half = nb >> 1;
    if (bid < half) {
      convert_weights(bid, half, a);
    } else {
      for (int j = bid - half; j < 260; j += nb - half)
        embed_job(j, a, smem);
    }
  }
  grid.sync();

  for (int l = 0; l < 3; ++l) {
    const u16* qw  = a.wbf + (size_t)l * 786432;
    const u16* ow  = a.wbf + 2359296 + (size_t)l * 262144;
    const u16* f1w = a.wbf + 3145728 + (size_t)l * 1048576;
    const u16* f2w = a.wbf + 6291456 + (size_t)l * 1048576;

    for (int j = bid; j < 408; j += nb)         // qkv: 24 x 17 tiles
      gemm_tile<1,0>(a.xsb, qw, a.qkv_b + l*1536, a.qkvbuf, nullptr, nullptr,
                     nullptr, BT, 1536, 512, j % 24, j / 24, 0, Asl, Bsl);
    grid.sync();

    for (int j = bid; j < 128; j += nb)         // attn: (b,h)
      attn_job(j, a.qkvbuf, a.obufb, smem);
    grid.sync();

    for (int j = bid; j < 272; j += nb)         // out: 8 x 17 x 2 splits
      gemm_tile<2,2>(a.obufb, ow, nullptr, a.part, nullptr, nullptr, nullptr,
                     BT, 512, 512, j % 8, (j / 8) % 17, j / 136, Asl, Bsl);
    grid.sync();

    for (int j = bid; j < 260; j += nb)         // ln1
      addln_job<2>(j, a.xs, a.xsb, a.part, a.out_b + l*512,
                   a.ln1_g + l*512, a.ln1_b + l*512);
    grid.sync();

    for (int j = bid; j < 544; j += nb)         // ff1: 32 x 17 tiles
      gemm_tile<1,1>(a.xsb, f1w, a.ff1_b + l*2048, nullptr, a.ffb, nullptr,
                     nullptr, BT, 2048, 512, j % 32, j / 32, 0, Asl, Bsl);
    grid.sync();

    for (int j = bid; j < 544; j += nb)         // ff2: 8 x 17 x 4 splits
      gemm_tile<4,2>(a.ffb, f2w, nullptr, a.part, nullptr, nullptr, nullptr,
                     BT, 512, 2048, j % 8, (j / 8) % 17, j / 136, Asl, Bsl);
    grid.sync();

    for (int j = bid; j < 260; j += nb)         // ln2
      addln_job<4>(j, a.xs, a.xsb, a.part, a.ff2_b + l*512,
                   a.ln2_g + l*512, a.ln2_b + l*512);
    grid.sync();
  }

  const u16* uhw = a.wbf + 9437184;
  for (int j = bid; j < 136; j += nb)           // u/h head: 8 x 17 tiles
    gemm_tile<1,3>(a.xsb, uhw, a.u_b, a.out, nullptr, a.hbuf, a.h_b,
                   BT, 512, 512, j % 8, j / 8, 0, Asl, Bsl);
  grid.sync();

  for (int j = bid; j < 256; j += nb)           // projection head
    proj_job(j, a.hbuf, a.marg, a.xg, a.out + 1040 * 256);
}

// ---------------------------------------------------------------------------
extern "C" void kernel_launch(void* const* d_in, const int* in_sizes, int n_in,
                              void* d_out, int out_size, void* d_ws, size_t ws_size,
                              hipStream_t stream)
{
  float* ws = (float*)d_ws;

  MegaArgs a;
  a.marg   = (const float*)d_in[0];
  a.xg     = (const float*)d_in[1];
  a.conv_w = (const float*)d_in[2];
  a.conv_b = (const float*)d_in[3];
  a.fc_w   = (const float*)d_in[4];
  a.fc_b   = (const float*)d_in[5];
  a.ln0_g  = (const float*)d_in[6];
  a.ln0_b  = (const float*)d_in[7];
  a.pos    = (const float*)d_in[8];
  a.qkv_w  = (const float*)d_in[9];
  a.qkv_b  = (const float*)d_in[10];
  a.out_w  = (const float*)d_in[11];
  a.out_b  = (const float*)d_in[12];
  a.ln1_g  = (const float*)d_in[13];
  a.ln1_b  = (const float*)d_in[14];
  a.ff1_w  = (const float*)d_in[15];
  a.ff1_b  = (const float*)d_in[16];
  a.ff2_w  = (const float*)d_in[17];
  a.ff2_b  = (const float*)d_in[18];
  a.ln2_g  = (const float*)d_in[19];
  a.ln2_b  = (const float*)d_in[20];
  a.u_w    = (const float*)d_in[21];
  a.u_b    = (const float*)d_in[22];
  a.h_w    = (const float*)d_in[23];
  a.h_b    = (const float*)d_in[24];
  a.out    = (float*)d_out;

  a.xs     = ws;                              // 532480 f32
  a.qkvbuf = ws + 532480;                     // 1597440 f32
  a.part   = ws + 2129920;                    // 4 x 532480 f32
  a.hbuf   = ws + 4259840;                    // 266240 f32
  a.xsb    = (u16*)(ws + 4526080);            // 532480 u16
  a.obufb  = (u16*)(ws + 4792320);            // 532480 u16
  a.ffb    = (u16*)(ws + 5058560);            // 2129920 u16
  a.wbf    = (u16*)(ws + 6123520);            // 9699328 u16

  int nblk = 0;
  hipOccupancyMaxActiveBlocksPerMultiprocessor(&nblk, mega, 256, 0);
  if (nblk < 1) nblk = 1;
  int gridsz = nblk * 256;
  if (gridsz > 544) gridsz = 544;             // largest stage = 544 jobs
  if (gridsz < 64)  gridsz = 64;

  void* kargs[] = { (void*)&a };
  hipLaunchCooperativeKernel(mega, dim3(gridsz), dim3(256), kargs, 0, stream);
}

// Round 4
// 570.791 us; speedup vs baseline: 1.8787x; 1.8787x over previous
//
#include <hip/hip_runtime.h>
#include <math.h>

// ---------------------------------------------------------------------------
// B=16, NP1=65, BT=1040, Mg=256, D=512, H=8, DH=64, L=3, DFF=2048
// R12: R11 resubmit, de-risked. Dispatches 24 -> 17 via row-stripe fusion:
//  - fused_row<512,0>: out-proj + out_b + residual + LN1  (65 blocks)
//  - fused_row<2048,0>: ff2 + ff2_b + residual + LN2      (65 blocks)
//  - fused_row<512,1>: u/h head + closed-form projection  (65 blocks)
// De-risks vs R11: fused_row stages A in <=1024-wide K chunks (32 KB LDS,
// not 64+), and EPI1 has no divergent __syncthreads (single uniform barrier).
// Each block owns 16 full rows: A-stripe in LDS, B streamed from L2 with
// 2-deep register prefetch, LN/proj via in-block cross-wave reduce.
// ---------------------------------------------------------------------------

#define BT   1040
#define NP1  65
#define Dm   512
#define MG   256

typedef short short8 __attribute__((ext_vector_type(8)));
typedef float f32x4  __attribute__((ext_vector_type(4)));
typedef unsigned short u16;

__device__ __forceinline__ u16 f2bf(float f) {
  unsigned int u = __float_as_uint(f);
  u += 0x7FFF + ((u >> 16) & 1);          // RNE
  return (u16)(u >> 16);
}

__device__ __forceinline__ float gelu_exact(float x) {
  return 0.5f * x * (1.0f + erff(x * 0.70710678118654752f));
}

__device__ __forceinline__ void async16(const u16* g, u16* l) {
  __builtin_amdgcn_global_load_lds(
      (const __attribute__((address_space(1))) unsigned int*)g,
      (__attribute__((address_space(3))) unsigned int*)l, 16, 0, 0);
}

__device__ __forceinline__ float wred(float v) {
#pragma unroll
  for (int o = 32; o; o >>= 1) v += __shfl_xor(v, o, 64);
  return v;
}

__device__ __forceinline__ float block_reduce_sum(float v, float* s) {
#pragma unroll
  for (int off = 32; off; off >>= 1) v += __shfl_down(v, off, 64);
  int lane = threadIdx.x & 63, wid = threadIdx.x >> 6;
  __syncthreads();
  if (lane == 0) s[wid] = v;
  __syncthreads();
  return s[0] + s[1] + s[2] + s[3];
}

// closed-form expected grid value under weights exp(-a*x_j/eps), x_j uniform:
__device__ __forceinline__ float f_closed(float a) {
  const float tf = 2.3529411765f;     // (6/255)*100
  float t = a * tf;
  float s = fabsf(t);
  float E;
  if (s < 1e-4f) {
    E = 127.5f - 5461.25f * t;        // series; kappa2=(256^2-1)/12
  } else {
    float u = s * 256.0f;
    float term2 = (u < 80.0f) ? 256.0f / expm1f(u) : 0.0f;
    float Epos = 1.0f / expm1f(s) - term2;
    E = (t > 0.0f) ? Epos : 255.0f - Epos;
  }
  return -3.0f + 0.0235294118f * E;   // delta = 6/255
}

// ---------------------------------------------------------------------------
// prep: blocks [0,512) convert weights fp32->bf16; blocks [512,772) embed
// ---------------------------------------------------------------------------
__global__ __launch_bounds__(256) void prep_kernel(
    const float* __restrict__ qkv_w, const float* __restrict__ out_w,
    const float* __restrict__ ff1_w, const float* __restrict__ ff2_w,
    const float* __restrict__ u_w,   const float* __restrict__ h_w,
    u16* __restrict__ wdst,
    const float* __restrict__ marg, const float* __restrict__ conv_w,
    const float* __restrict__ conv_b, const float* __restrict__ fc_w,
    const float* __restrict__ fc_b, const float* __restrict__ g,
    const float* __restrict__ bb, const float* __restrict__ pos,
    float* __restrict__ xs, u16* __restrict__ xsb)
{
  const int tid = threadIdx.x;
  if (blockIdx.x < 512) {
    const size_t O1 = 2359296, O2 = 3145728, O3 = 6291456;
    const size_t O4 = 9437184, O5 = 9568256, TOT4 = 9699328 / 4;
    for (size_t e4 = (size_t)blockIdx.x * 256 + tid; e4 < TOT4;
         e4 += (size_t)512 * 256) {
      size_t e = e4 * 4;
      const float* src;
      if      (e < O1) src = qkv_w + e;
      else if (e < O2) src = out_w + (e - O1);
      else if (e < O3) src = ff1_w + (e - O2);
      else if (e < O4) src = ff2_w + (e - O3);
      else if (e < O5) src = u_w   + (e - O4);
      else             src = h_w   + (e - O5);
      float4 v = *(const float4*)src;
      unsigned int lo = (unsigned int)f2bf(v.x) | ((unsigned int)f2bf(v.y) << 16);
      unsigned int hi = (unsigned int)f2bf(v.z) | ((unsigned int)f2bf(v.w) << 16);
      *(uint2*)(wdst + e) = make_uint2(lo, hi);
    }
    return;
  }
  // ---- embed: 4 tokens per block ----
  __shared__ float es[4][128];
  __shared__ float sS[4];
  __shared__ float edge[4][4];
  __shared__ float red[4];
  const int t0 = (blockIdx.x - 512) * 4;
  const int lane = tid & 63, wave = tid >> 6;
  {
    float4 mv = *(const float4*)(marg + (size_t)(t0 + wave) * MG + lane * 4);
    float S = wred(mv.x + mv.y + mv.z + mv.w);
    if (lane == 0) sS[wave] = S;
  }
  if (tid < 16) {
    int k = tid >> 2, e = tid & 3;
    int idx = (e < 2) ? e : (e + 252);       // 0,1,254,255
    edge[k][e] = marg[(size_t)(t0 + k) * MG + idx];
  }
  __syncthreads();
  if (tid < 128) {
    int o = tid;
    float w0 = conv_w[o*5+0], w1 = conv_w[o*5+1], w2 = conv_w[o*5+2];
    float w3 = conv_w[o*5+3], w4 = conv_w[o*5+4], cb = conv_b[o];
#pragma unroll
    for (int k = 0; k < 4; ++k) {
      float S = sS[k];
      float x0 = edge[k][0], x1 = edge[k][1], x254 = edge[k][2], x255 = edge[k][3];
      es[k][o] = (w0*(S - x254 - x255) + w1*(S - x255) + w2*S
                + w3*(S - x0) + w4*(S - x0 - x1)) * (1.0f/256.0f) + cb;
    }
  }
  __syncthreads();
  float b0 = fc_b[tid], b1 = fc_b[tid + 256];
  float z[4][2];
#pragma unroll
  for (int k = 0; k < 4; ++k) { z[k][0] = b0; z[k][1] = b1; }
#pragma unroll 4
  for (int o = 0; o < 128; ++o) {
    float f0 = fc_w[(size_t)o*Dm + tid];
    float f1 = fc_w[(size_t)o*Dm + tid + 256];
#pragma unroll
    for (int k = 0; k < 4; ++k) {
      float e = es[k][o];
      z[k][0] += e * f0; z[k][1] += e * f1;
    }
  }
  float g0 = g[tid], g1 = g[tid+256], e0 = bb[tid], e1 = bb[tid+256];
#pragma unroll
  for (int k = 0; k < 4; ++k) {
    float mu = block_reduce_sum(z[k][0] + z[k][1], red) * (1.0f/512.0f);
    float d0 = z[k][0] - mu, d1 = z[k][1] - mu;
    float var = block_reduce_sum(d0*d0 + d1*d1, red) * (1.0f/512.0f);
    float inv = rsqrtf(var + 1e-5f);
    int t = t0 + k, p = t % NP1;
    float y0 = gelu_exact(d0*inv*g0 + e0) + pos[(size_t)p*Dm + tid];
    float y1 = gelu_exact(d1*inv*g1 + e1) + pos[(size_t)p*Dm + tid + 256];
    xs[(size_t)t*Dm + tid]        = y0;
    xs[(size_t)t*Dm + tid + 256]  = y1;
    xsb[(size_t)t*Dm + tid]       = f2bf(y0);
    xsb[(size_t)t*Dm + tid + 256] = f2bf(y1);
  }
}

// ---------------------------------------------------------------------------
// 64x64 MFMA tile GEMM (qkv, ff1), BK=64, async16 dbuf staging, 4 waves 2x2.
// MODE: 0 fp32 v+bias | 1 bf16 gelu(v+bias)
// ---------------------------------------------------------------------------
template<int MODE>
__global__ __launch_bounds__(256) void gemm_mfma(
    const u16* __restrict__ A, const u16* __restrict__ Bw,
    const float* __restrict__ bias, float* __restrict__ Cf,
    u16* __restrict__ Cb, int Mrows, int N, int K)
{
  __shared__ u16 Asl[2][8*64*8];
  __shared__ u16 Bsl[2][8*64*8];
  const int tid = threadIdx.x;
  const int row0 = blockIdx.y * 64, col0 = blockIdx.x * 64;
  const int lane = tid & 63, wave = tid >> 6;
  const int wm = (wave >> 1) * 32, wn = (wave & 1) * 32;
  const int l15 = lane & 15, q = lane >> 4;

  f32x4 acc[2][2];
  acc[0][0] = (f32x4){0,0,0,0}; acc[0][1] = (f32x4){0,0,0,0};
  acc[1][0] = (f32x4){0,0,0,0}; acc[1][1] = (f32x4){0,0,0,0};

  const int arow = min(row0 + lane, Mrows - 1);
  const size_t abase = (size_t)arow * K;
  const size_t bbase = (size_t)(col0 + lane) * K;
  const int c0w = wave * 2;

#pragma unroll
  for (int i = 0; i < 2; ++i) {
    int c = c0w + i;
    async16(A + abase + c * 8, &Asl[0][(size_t)(c * 64 + lane) * 8]);
    async16(Bw + bbase + c * 8, &Bsl[0][(size_t)(c * 64 + lane) * 8]);
  }

  const int nk = K >> 6;
  for (int t = 0; t < nk; ++t) {
    const int cur = t & 1;
    if (t + 1 < nk) {
      const int nxt = cur ^ 1;
      const int kk = (t + 1) * 64;
#pragma unroll
      for (int i = 0; i < 2; ++i) {
        int c = c0w + i;
        async16(A + abase + kk + c * 8, &Asl[nxt][(size_t)(c*64 + lane)*8]);
        async16(Bw + bbase + kk + c * 8, &Bsl[nxt][(size_t)(c*64 + lane)*8]);
      }
      asm volatile("s_waitcnt vmcnt(4)" ::: "memory");
    } else {
      asm volatile("s_waitcnt vmcnt(0)" ::: "memory");
    }
    __builtin_amdgcn_s_barrier();
#pragma unroll
    for (int tt = 0; tt < 2; ++tt) {
      int cc = tt * 4 + q;
      short8 af[2], bf[2];
#pragma unroll
      for (int mi = 0; mi < 2; ++mi)
        af[mi] = *(short8*)&Asl[cur][(size_t)(cc*64 + wm + mi*16 + l15) * 8];
#pragma unroll
      for (int ni = 0; ni < 2; ++ni)
        bf[ni] = *(short8*)&Bsl[cur][(size_t)(cc*64 + wn + ni*16 + l15) * 8];
#pragma unroll
      for (int mi = 0; mi < 2; ++mi)
#pragma unroll
        for (int ni = 0; ni < 2; ++ni)
          acc[mi][ni] = __builtin_amdgcn_mfma_f32_16x16x32_bf16(
              af[mi], bf[ni], acc[mi][ni], 0, 0, 0);
    }
    __builtin_amdgcn_s_barrier();
  }

#pragma unroll
  for (int mi = 0; mi < 2; ++mi) {
#pragma unroll
    for (int ni = 0; ni < 2; ++ni) {
      int col = col0 + wn + ni*16 + l15;
#pragma unroll
      for (int r = 0; r < 4; ++r) {
        int row = row0 + wm + mi*16 + q*4 + r;
        if (row < Mrows) {
          float v = acc[mi][ni][r];
          if (MODE == 0) {
            Cf[(size_t)row*N + col] = v + bias[col];
          } else {
            Cb[(size_t)row*N + col] = f2bf(gelu_exact(v + bias[col]));
          }
        }
      }
    }
  }
}

// ---------------------------------------------------------------------------
// fused_row<KK,EPI>: block owns 16 rows x 512 cols, K=KK.
// A-stripe staged to LDS in <=1024-wide K chunks (32 KB); B streamed from
// global/L2 with 2-deep register prefetch; 8 n-frags per wave (128 cols).
// EPI 0: v+bias+residual(xs) -> LN(g,bb) -> xs,xsb
// EPI 1: cols<256: u_pot=v+bias -> outu ; cols>=256: h=v+bias2 -> closed-form
//        projection (corr over 256 grid cols, waves 2&3) -> outh
// ---------------------------------------------------------------------------
template<int KK, int EPI>
__global__ __launch_bounds__(256) void fused_row(
    const u16* __restrict__ A, const u16* __restrict__ Bw,
    const float* __restrict__ bias,
    float* __restrict__ xs, u16* __restrict__ xsb,
    const float* __restrict__ g, const float* __restrict__ bb,
    const float* __restrict__ bias2,
    const float* __restrict__ marg, const float* __restrict__ xg,
    float* __restrict__ outu, float* __restrict__ outh)
{
  constexpr int KC  = (KK < 1024) ? KK : 1024;   // K-chunk staged in LDS
  constexpr int NCH = KK / KC;
  __shared__ u16 Alds[16 * KC];                  // <= 32 KB
  __shared__ float red[4][16];
  __shared__ float red2[4][16];
  const int tid = threadIdx.x, lane = tid & 63, wave = tid >> 6;
  const int l15 = lane & 15, q = lane >> 4;
  const int r0 = blockIdx.x * 16;
  const int gc0 = wave * 128;

  f32x4 acc[8];
#pragma unroll
  for (int i = 0; i < 8; ++i) acc[i] = (f32x4){0,0,0,0};

  for (int ch = 0; ch < NCH; ++ch) {
    const int kc = ch * KC;
    __syncthreads();                 // Alds reuse guard (no-op cost at ch=0)
    // ---- stage A chunk: chunk-major [c][16 rows][8 u16] ----
    for (int idx = tid; idx < 2 * KC; idx += 256) {
      int r = idx & 15, c = idx >> 4;
      async16(A + (size_t)(r0 + r) * KK + kc + c * 8, &Alds[(size_t)idx * 8]);
    }
    asm volatile("s_waitcnt vmcnt(0)" ::: "memory");
    __syncthreads();

    constexpr int S = KC / 32;
    short8 bcur[8], bnxt[8];
#pragma unroll
    for (int i = 0; i < 8; ++i)
      bcur[i] = *(const short8*)&Bw[(size_t)(gc0 + i*16 + l15) * KK + kc + q * 8];
    for (int s = 0; s < S; ++s) {
      if (s + 1 < S) {
#pragma unroll
        for (int i = 0; i < 8; ++i)
          bnxt[i] = *(const short8*)&Bw[(size_t)(gc0 + i*16 + l15) * KK
                                        + kc + ((s + 1) * 4 + q) * 8];
      }
      short8 af = *(const short8*)&Alds[(size_t)((s * 4 + q) * 16 + l15) * 8];
#pragma unroll
      for (int i = 0; i < 8; ++i)
        acc[i] = __builtin_amdgcn_mfma_f32_16x16x32_bf16(af, bcur[i], acc[i], 0, 0, 0);
#pragma unroll
      for (int i = 0; i < 8; ++i) bcur[i] = bnxt[i];
    }
  }

  // lane's elements: row = q*4+r (local), col = gc0 + i*16 + l15
  if (EPI == 0) {
    float vv[8][4];
#pragma unroll
    for (int i = 0; i < 8; ++i) {
      int col = gc0 + i*16 + l15;
      float bcol = bias[col];
#pragma unroll
      for (int r = 0; r < 4; ++r) {
        int gr = r0 + q*4 + r;
        vv[i][r] = acc[i][r] + bcol + xs[(size_t)gr * Dm + col];
      }
    }
    // mean
    float ps[4];
#pragma unroll
    for (int r = 0; r < 4; ++r) {
      float s = 0.f;
#pragma unroll
      for (int i = 0; i < 8; ++i) s += vv[i][r];
      ps[r] = s;
    }
#pragma unroll
    for (int o = 1; o < 16; o <<= 1)
#pragma unroll
      for (int r = 0; r < 4; ++r) ps[r] += __shfl_xor(ps[r], o, 64);
    if (l15 == 0)
#pragma unroll
      for (int r = 0; r < 4; ++r) red[wave][q*4 + r] = ps[r];
    __syncthreads();
    float mu[4];
#pragma unroll
    for (int r = 0; r < 4; ++r) {
      int rr = q*4 + r;
      mu[r] = (red[0][rr] + red[1][rr] + red[2][rr] + red[3][rr]) * (1.0f/512.0f);
    }
    // variance
    float ps2[4];
#pragma unroll
    for (int r = 0; r < 4; ++r) {
      float s = 0.f;
#pragma unroll
      for (int i = 0; i < 8; ++i) { float d = vv[i][r] - mu[r]; s += d * d; }
      ps2[r] = s;
    }
#pragma unroll
    for (int o = 1; o < 16; o <<= 1)
#pragma unroll
      for (int r = 0; r < 4; ++r) ps2[r] += __shfl_xor(ps2[r], o, 64);
    if (l15 == 0)
#pragma unroll
      for (int r = 0; r < 4; ++r) red2[wave][q*4 + r] = ps2[r];
    __syncthreads();
    float inv[4];
#pragma unroll
    for (int r = 0; r < 4; ++r) {
      int rr = q*4 + r;
      inv[r] = rsqrtf((red2[0][rr] + red2[1][rr] + red2[2][rr] + red2[3][rr])
                      * (1.0f/512.0f) + 1e-5f);
    }
#pragma unroll
    for (int i = 0; i < 8; ++i) {
      int col = gc0 + i*16 + l15;
      float gc = g[col], bc = bb[col];
#pragma unroll
      for (int r = 0; r < 4; ++r) {
        int gr = r0 + q*4 + r;
        float y = (vv[i][r] - mu[r]) * inv[r] * gc + bc;
        xs[(size_t)gr * Dm + col] = y;
        xsb[(size_t)gr * Dm + col] = f2bf(y);
      }
    }
  } else {
    // EPI 1: u/h head + projection. No divergent barriers: waves 2/3 reduce,
    // one uniform barrier, then both groups write.
    float va[8][4];
    if (wave >= 2) {
      float wd[4] = {0.f,0.f,0.f,0.f}, ms[4] = {0.f,0.f,0.f,0.f};
#pragma unroll
      for (int i = 0; i < 8; ++i) {
        int hcol = (gc0 - 256) + i*16 + l15;
        float bcol = bias2[hcol];
        float xv = xg[hcol];
#pragma unroll
        for (int r = 0; r < 4; ++r) {
          int gr = r0 + q*4 + r;
          float a = acc[i][r] + bcol;
          va[i][r] = a;
          float uvm = marg[(size_t)gr * MG + hcol];
          wd[r] += uvm * (f_closed(a) - xv);
          ms[r] += uvm;
        }
      }
#pragma unroll
      for (int o = 1; o < 16; o <<= 1)
#pragma unroll
        for (int r = 0; r < 4; ++r) {
          wd[r] += __shfl_xor(wd[r], o, 64);
          ms[r] += __shfl_xor(ms[r], o, 64);
        }
      if (l15 == 0)
#pragma unroll
        for (int r = 0; r < 4; ++r) {
          red[wave][q*4 + r]  = wd[r];
          red2[wave][q*4 + r] = ms[r];
        }
    }
    __syncthreads();
    if (wave < 2) {
      // u_pot: cols 0..255
#pragma unroll
      for (int i = 0; i < 8; ++i) {
        int col = gc0 + i*16 + l15;
        float bcol = bias[col];
#pragma unroll
        for (int r = 0; r < 4; ++r) {
          int gr = r0 + q*4 + r;
          outu[(size_t)gr * MG + col] = acc[i][r] + bcol;
        }
      }
    } else {
#pragma unroll
      for (int i = 0; i < 8; ++i) {
        int hcol = (gc0 - 256) + i*16 + l15;
#pragma unroll
        for (int r = 0; r < 4; ++r) {
          int rr = q*4 + r;
          int gr = r0 + rr;
          int b = gr / NP1, n = gr - b * NP1;
          if (n < 64) {
            float corr = (red[2][rr] + red[3][rr])
                       / (red2[2][rr] + red2[3][rr] + 1e-8f);
            outh[(size_t)(b * 64 + n) * MG + hcol] = va[i][r] - corr;
          }
        }
      }
    }
  }
}

// ---------------------------------------------------------------------------
// Attention: one block per (b,h); fp32 in LDS; writes obuf bf16
// ---------------------------------------------------------------------------
__global__ __launch_bounds__(256) void attn_kernel(
    const float* __restrict__ qkv, u16* __restrict__ obufb)
{
  __shared__ float qv[65][67];
  __shared__ float ks[65][67];
  __shared__ float ss[65][67];
  const int b = blockIdx.x >> 3, h = blockIdx.x & 7;
  const int tid = threadIdx.x;
  const float* base = qkv + (size_t)b * NP1 * 1536 + h * 64;
  for (int idx = tid; idx < NP1 * 16; idx += 256) {
    int t = idx >> 4, c = (idx & 15) << 2;
    const float* p = base + (size_t)t * 1536 + c;
    float4 q4 = *(const float4*)(p);
    float4 k4 = *(const float4*)(p + 512);
    qv[t][c] = q4.x; qv[t][c+1] = q4.y; qv[t][c+2] = q4.z; qv[t][c+3] = q4.w;
    ks[t][c] = k4.x; ks[t][c+1] = k4.y; ks[t][c+2] = k4.z; ks[t][c+3] = k4.w;
  }
  __syncthreads();
#pragma unroll
  for (int it = 0; it < 2; ++it) {
    int tile = it * 256 + tid;
    if (tile < 289) {
      int ti = (tile / 17) * 4, tj = (tile % 17) * 4;
      const float* qr[4]; const float* kr[4];
#pragma unroll
      for (int i = 0; i < 4; ++i) { qr[i] = qv[min(ti + i, 64)]; kr[i] = ks[min(tj + i, 64)]; }
      float acc[4][4] = {};
      for (int d = 0; d < 64; ++d) {
        float a[4], bvv[4];
#pragma unroll
        for (int i = 0; i < 4; ++i) { a[i] = qr[i][d]; bvv[i] = kr[i][d]; }
#pragma unroll
        for (int i = 0; i < 4; ++i)
#pragma unroll
          for (int j = 0; j < 4; ++j) acc[i][j] += a[i] * bvv[j];
      }
#pragma unroll
      for (int i = 0; i < 4; ++i)
        if (ti + i < 65)
#pragma unroll
          for (int j = 0; j < 4; ++j)
            if (tj + j < 65) ss[ti + i][tj + j] = acc[i][j] * 0.125f;
    }
  }
  __syncthreads();
  for (int idx = tid; idx < NP1 * 16; idx += 256) {
    int t = idx >> 4, c = (idx & 15) << 2;
    float4 v4 = *(const float4*)(base + (size_t)t * 1536 + 1024 + c);
    qv[t][c] = v4.x; qv[t][c+1] = v4.y; qv[t][c+2] = v4.z; qv[t][c+3] = v4.w;
  }
  if (tid < 65) {
    float mx = -1e30f;
    for (int j = 0; j < 65; ++j) mx = fmaxf(mx, ss[tid][j]);
    float s = 0.0f;
    for (int j = 0; j < 65; ++j) { float e = expf(ss[tid][j] - mx); ss[tid][j] = e; s += e; }
    float inv = 1.0f / s;
    for (int j = 0; j < 65; ++j) ss[tid][j] *= inv;
  }
  __syncthreads();
#pragma unroll
  for (int it = 0; it < 2; ++it) {
    int tile = it * 256 + tid;
    if (tile < 272) {
      int ti = (tile >> 4) * 4, d0 = (tile & 15) * 4;
      const float* sr[4];
#pragma unroll
      for (int i = 0; i < 4; ++i) sr[i] = ss[min(ti + i, 64)];
      float acc[4][4] = {};
      for (int j = 0; j < 65; ++j) {
        float v0 = qv[j][d0], v1 = qv[j][d0+1], v2 = qv[j][d0+2], v3 = qv[j][d0+3];
#pragma unroll
        for (int i = 0; i < 4; ++i) {
          float s = sr[i][j];
          acc[i][0] += s * v0; acc[i][1] += s * v1;
          acc[i][2] += s * v2; acc[i][3] += s * v3;
        }
      }
#pragma unroll
      for (int i = 0; i < 4; ++i)
        if (ti + i < 65) {
          ushort4 o;
          o.x = f2bf(acc[i][0]); o.y = f2bf(acc[i][1]);
          o.z = f2bf(acc[i][2]); o.w = f2bf(acc[i][3]);
          *(ushort4*)(obufb + (size_t)(b * NP1 + ti + i) * Dm + h * 64 + d0) = o;
        }
    }
  }
}

// ---------------------------------------------------------------------------
extern "C" void kernel_launch(void* const* d_in, const int* in_sizes, int n_in,
                              void* d_out, int out_size, void* d_ws, size_t ws_size,
                              hipStream_t stream)
{
  const float* marg   = (const float*)d_in[0];
  const float* xg     = (const float*)d_in[1];
  const float* conv_w = (const float*)d_in[2];
  const float* conv_b = (const float*)d_in[3];
  const float* fc_w   = (const float*)d_in[4];
  const float* fc_b   = (const float*)d_in[5];
  const float* ln0_g  = (const float*)d_in[6];
  const float* ln0_b  = (const float*)d_in[7];
  const float* pos    = (const float*)d_in[8];
  const float* qkv_w  = (const float*)d_in[9];
  const float* qkv_b  = (const float*)d_in[10];
  const float* out_w  = (const float*)d_in[11];
  const float* out_b  = (const float*)d_in[12];
  const float* ln1_g  = (const float*)d_in[13];
  const float* ln1_b  = (const float*)d_in[14];
  const float* ff1_w  = (const float*)d_in[15];
  const float* ff1_b  = (const float*)d_in[16];
  const float* ff2_w  = (const float*)d_in[17];
  const float* ff2_b  = (const float*)d_in[18];
  const float* ln2_g  = (const float*)d_in[19];
  const float* ln2_b  = (const float*)d_in[20];
  const float* u_w    = (const float*)d_in[21];
  const float* u_b    = (const float*)d_in[22];
  const float* h_w    = (const float*)d_in[23];
  const float* h_b    = (const float*)d_in[24];
  float* out = (float*)d_out;

  float* ws = (float*)d_ws;
  float* xs      = ws;                              // 532480 f32
  float* qkvbuf  = ws + 532480;                     // 1597440 f32
  u16*   xsb     = (u16*)(ws + 4526080);            // 532480 u16
  u16*   obufb   = (u16*)(ws + 4792320);            // 532480 u16
  u16*   ffb     = (u16*)(ws + 5058560);            // 2129920 u16
  u16*   wbf     = (u16*)(ws + 6123520);            // 9699328 u16

  const u16* qkv_bw = wbf;
  const u16* out_bw = wbf + 2359296;
  const u16* ff1_bw = wbf + 3145728;
  const u16* ff2_bw = wbf + 6291456;
  const u16* uh_bw  = wbf + 9437184;   // u rows 0..255, h rows 256..511

  prep_kernel<<<772, 256, 0, stream>>>(
      qkv_w, out_w, ff1_w, ff2_w, u_w, h_w, wbf,
      marg, conv_w, conv_b, fc_w, fc_b, ln0_g, ln0_b, pos, xs, xsb);

  for (int l = 0; l < 3; ++l) {
    gemm_mfma<0><<<dim3(24, 17), 256, 0, stream>>>(
        xsb, qkv_bw + (size_t)l*786432, qkv_b + l*1536, qkvbuf,
        nullptr, BT, 1536, 512);
    attn_kernel<<<128, 256, 0, stream>>>(qkvbuf, obufb);
    fused_row<512, 0><<<65, 256, 0, stream>>>(
        obufb, out_bw + (size_t)l*262144, out_b + l*512,
        xs, xsb, ln1_g + l*512, ln1_b + l*512,
        nullptr, nullptr, nullptr, nullptr, nullptr);
    gemm_mfma<1><<<dim3(32, 17), 256, 0, stream>>>(
        xsb, ff1_bw + (size_t)l*1048576, ff1_b + l*2048, nullptr,
        ffb, BT, 2048, 512);
    fused_row<2048, 0><<<65, 256, 0, stream>>>(
        ffb, ff2_bw + (size_t)l*1048576, ff2_b + l*512,
        xs, xsb, ln2_g + l*512, ln2_b + l*512,
        nullptr, nullptr, nullptr, nullptr, nullptr);
  }

  fused_row<512, 1><<<65, 256, 0, stream>>>(
      xsb, uh_bw, u_b,
      nullptr, nullptr, nullptr, nullptr,
      h_b, marg, xg, out, out + 1040*256);
}

// Round 5
// 420.586 us; speedup vs baseline: 2.5496x; 1.3571x over previous
//
#include <hip/hip_runtime.h>
#include <math.h>

// ---------------------------------------------------------------------------
// B=16, NP1=65, BT=1040, Mg=256, D=512, H=8, DH=64, L=3, DFF=2048
// R13: MFMA-tile-chunk PACKING of all bf16 operands. R12's profile showed
// fused_row<2048> at 63.6us with all pipes idle: row-major fragment loads
// fragment into 16 coalescing groups (64B each) per instruction -> CU texture
// pipe issue-bound. Packed layout P[nb][kb][c][n64][e8] makes gemm staging
// contiguous 1KB/instr and fused_row B-streams 4x256B/instr.
// 17 dispatches, same math, absmax unchanged.
// ---------------------------------------------------------------------------

#define BT   1040
#define NP1  65
#define Dm   512
#define MG   256

typedef short short8 __attribute__((ext_vector_type(8)));
typedef float f32x4  __attribute__((ext_vector_type(4)));
typedef unsigned short u16;

// packed u16 index of element (r, c) in a [R][C] bf16 matrix, KB = C/64
__device__ __forceinline__ size_t pidx(int r, int c, int KB) {
  return ((size_t)((r >> 6) * KB + (c >> 6)) * 8 + ((c & 63) >> 3)) * 512
       + (size_t)((r & 63) * 8 + (c & 7));
}

__device__ __forceinline__ u16 f2bf(float f) {
  unsigned int u = __float_as_uint(f);
  u += 0x7FFF + ((u >> 16) & 1);          // RNE
  return (u16)(u >> 16);
}

__device__ __forceinline__ float gelu_exact(float x) {
  return 0.5f * x * (1.0f + erff(x * 0.70710678118654752f));
}

__device__ __forceinline__ void async16(const u16* g, u16* l) {
  __builtin_amdgcn_global_load_lds(
      (const __attribute__((address_space(1))) unsigned int*)g,
      (__attribute__((address_space(3))) unsigned int*)l, 16, 0, 0);
}

__device__ __forceinline__ float wred(float v) {
#pragma unroll
  for (int o = 32; o; o >>= 1) v += __shfl_xor(v, o, 64);
  return v;
}

__device__ __forceinline__ float block_reduce_sum(float v, float* s) {
#pragma unroll
  for (int off = 32; off; off >>= 1) v += __shfl_down(v, off, 64);
  int lane = threadIdx.x & 63, wid = threadIdx.x >> 6;
  __syncthreads();
  if (lane == 0) s[wid] = v;
  __syncthreads();
  return s[0] + s[1] + s[2] + s[3];
}

// closed-form expected grid value under weights exp(-a*x_j/eps), x_j uniform:
__device__ __forceinline__ float f_closed(float a) {
  const float tf = 2.3529411765f;     // (6/255)*100
  float t = a * tf;
  float s = fabsf(t);
  float E;
  if (s < 1e-4f) {
    E = 127.5f - 5461.25f * t;        // series; kappa2=(256^2-1)/12
  } else {
    float u = s * 256.0f;
    float term2 = (u < 80.0f) ? 256.0f / expm1f(u) : 0.0f;
    float Epos = 1.0f / expm1f(s) - term2;
    E = (t > 0.0f) ? Epos : 255.0f - Epos;
  }
  return -3.0f + 0.0235294118f * E;   // delta = 6/255
}

// ---------------------------------------------------------------------------
// prep: blocks [0,512) convert+PACK weights fp32->bf16; [512,772) embed
// packed matrices (u16 offsets): qkv [4608][512] @0 | out [1536][512] @2359296
// | ff1 [6144][512] @3145728 | ff2 [1536][2048] @6291456 | uh [512][512]
// @9437184 (u rows 0..255, h rows 256..511). Layer offsets unchanged.
// ---------------------------------------------------------------------------
__global__ __launch_bounds__(256) void prep_kernel(
    const float* __restrict__ qkv_w, const float* __restrict__ out_w,
    const float* __restrict__ ff1_w, const float* __restrict__ ff2_w,
    const float* __restrict__ u_w,   const float* __restrict__ h_w,
    u16* __restrict__ wdst,
    const float* __restrict__ marg, const float* __restrict__ conv_w,
    const float* __restrict__ conv_b, const float* __restrict__ fc_w,
    const float* __restrict__ fc_b, const float* __restrict__ g,
    const float* __restrict__ bb, const float* __restrict__ pos,
    float* __restrict__ xs, u16* __restrict__ xsb)
{
  const int tid = threadIdx.x;
  if (blockIdx.x < 512) {
    const size_t O1 = 2359296, O2 = 3145728, O3 = 6291456;
    const size_t O4 = 9437184, O5 = 9568256, TOT4 = 9699328 / 4;
    for (size_t e4 = (size_t)blockIdx.x * 256 + tid; e4 < TOT4;
         e4 += (size_t)512 * 256) {
      size_t e = e4 * 4;
      const float* src; size_t base; int n, k, KB;
      if (e < O1)      { size_t r = e;      src = qkv_w + r; base = 0;
                         n = (int)(r >> 9);  k = (int)(r & 511);  KB = 8; }
      else if (e < O2) { size_t r = e - O1; src = out_w + r; base = O1;
                         n = (int)(r >> 9);  k = (int)(r & 511);  KB = 8; }
      else if (e < O3) { size_t r = e - O2; src = ff1_w + r; base = O2;
                         n = (int)(r >> 9);  k = (int)(r & 511);  KB = 8; }
      else if (e < O4) { size_t r = e - O3; src = ff2_w + r; base = O3;
                         n = (int)(r >> 11); k = (int)(r & 2047); KB = 32; }
      else if (e < O5) { size_t r = e - O4; src = u_w + r;   base = O4;
                         n = (int)(r >> 9);  k = (int)(r & 511);  KB = 8; }
      else             { size_t r = e - O5; src = h_w + r;   base = O4;
                         n = 256 + (int)(r >> 9); k = (int)(r & 511); KB = 8; }
      float4 v = *(const float4*)src;
      unsigned int lo = (unsigned int)f2bf(v.x) | ((unsigned int)f2bf(v.y) << 16);
      unsigned int hi = (unsigned int)f2bf(v.z) | ((unsigned int)f2bf(v.w) << 16);
      *(uint2*)(wdst + base + pidx(n, k, KB)) = make_uint2(lo, hi);
    }
    return;
  }
  // ---- embed: 4 tokens per block ----
  __shared__ float es[4][128];
  __shared__ float sS[4];
  __shared__ float edge[4][4];
  __shared__ float red[4];
  const int t0 = (blockIdx.x - 512) * 4;
  const int lane = tid & 63, wave = tid >> 6;
  {
    float4 mv = *(const float4*)(marg + (size_t)(t0 + wave) * MG + lane * 4);
    float S = wred(mv.x + mv.y + mv.z + mv.w);
    if (lane == 0) sS[wave] = S;
  }
  if (tid < 16) {
    int k = tid >> 2, e = tid & 3;
    int idx = (e < 2) ? e : (e + 252);       // 0,1,254,255
    edge[k][e] = marg[(size_t)(t0 + k) * MG + idx];
  }
  __syncthreads();
  if (tid < 128) {
    int o = tid;
    float w0 = conv_w[o*5+0], w1 = conv_w[o*5+1], w2 = conv_w[o*5+2];
    float w3 = conv_w[o*5+3], w4 = conv_w[o*5+4], cb = conv_b[o];
#pragma unroll
    for (int k = 0; k < 4; ++k) {
      float S = sS[k];
      float x0 = edge[k][0], x1 = edge[k][1], x254 = edge[k][2], x255 = edge[k][3];
      es[k][o] = (w0*(S - x254 - x255) + w1*(S - x255) + w2*S
                + w3*(S - x0) + w4*(S - x0 - x1)) * (1.0f/256.0f) + cb;
    }
  }
  __syncthreads();
  float b0 = fc_b[tid], b1 = fc_b[tid + 256];
  float z[4][2];
#pragma unroll
  for (int k = 0; k < 4; ++k) { z[k][0] = b0; z[k][1] = b1; }
#pragma unroll 4
  for (int o = 0; o < 128; ++o) {
    float f0 = fc_w[(size_t)o*Dm + tid];
    float f1 = fc_w[(size_t)o*Dm + tid + 256];
#pragma unroll
    for (int k = 0; k < 4; ++k) {
      float e = es[k][o];
      z[k][0] += e * f0; z[k][1] += e * f1;
    }
  }
  float g0 = g[tid], g1 = g[tid+256], e0 = bb[tid], e1 = bb[tid+256];
#pragma unroll
  for (int k = 0; k < 4; ++k) {
    float mu = block_reduce_sum(z[k][0] + z[k][1], red) * (1.0f/512.0f);
    float d0 = z[k][0] - mu, d1 = z[k][1] - mu;
    float var = block_reduce_sum(d0*d0 + d1*d1, red) * (1.0f/512.0f);
    float inv = rsqrtf(var + 1e-5f);
    int t = t0 + k, p = t % NP1;
    float y0 = gelu_exact(d0*inv*g0 + e0) + pos[(size_t)p*Dm + tid];
    float y1 = gelu_exact(d1*inv*g1 + e1) + pos[(size_t)p*Dm + tid + 256];
    xs[(size_t)t*Dm + tid]        = y0;
    xs[(size_t)t*Dm + tid + 256]  = y1;
    xsb[pidx(t, tid, 8)]          = f2bf(y0);
    xsb[pidx(t, tid + 256, 8)]    = f2bf(y1);
  }
}

// ---------------------------------------------------------------------------
// 64x64 MFMA tile GEMM (qkv, ff1), BK=64, packed A and B: async16 staging is
// contiguous 1KB per instruction. 4 waves 2x2 (wave tile 32x32), dbuf.
// MODE: 0 fp32 v+bias (linear C) | 1 bf16 gelu(v+bias) -> PACKED Cb (KB=32)
// ---------------------------------------------------------------------------
template<int MODE>
__global__ __launch_bounds__(256) void gemm_mfma(
    const u16* __restrict__ A, const u16* __restrict__ Bw,
    const float* __restrict__ bias, float* __restrict__ Cf,
    u16* __restrict__ Cb, int Mrows, int N, int K)
{
  __shared__ u16 Asl[2][4096];
  __shared__ u16 Bsl[2][4096];
  const int tid = threadIdx.x;
  const int row0 = blockIdx.y * 64, col0 = blockIdx.x * 64;
  const int lane = tid & 63, wave = tid >> 6;
  const int wm = (wave >> 1) * 32, wn = (wave & 1) * 32;
  const int l15 = lane & 15, q = lane >> 4;
  const int KB = K >> 6;

  f32x4 acc[2][2];
  acc[0][0] = (f32x4){0,0,0,0}; acc[0][1] = (f32x4){0,0,0,0};
  acc[1][0] = (f32x4){0,0,0,0}; acc[1][1] = (f32x4){0,0,0,0};

  const size_t abase = (size_t)blockIdx.y * KB * 4096 + (size_t)lane * 8;
  const size_t bbase = (size_t)blockIdx.x * KB * 4096 + (size_t)lane * 8;
  const int c0w = wave * 2;

  // prologue: stage buf0 (contiguous 1KB per async16)
#pragma unroll
  for (int i = 0; i < 2; ++i) {
    int c = c0w + i;
    async16(A + abase + (size_t)c * 512, &Asl[0][(size_t)(c * 64 + lane) * 8]);
    async16(Bw + bbase + (size_t)c * 512, &Bsl[0][(size_t)(c * 64 + lane) * 8]);
  }

  const int nk = K >> 6;
  for (int t = 0; t < nk; ++t) {
    const int cur = t & 1;
    if (t + 1 < nk) {
      const int nxt = cur ^ 1;
#pragma unroll
      for (int i = 0; i < 2; ++i) {
        int c = c0w + i;
        async16(A + abase + (size_t)((t + 1) * 8 + c) * 512,
                &Asl[nxt][(size_t)(c * 64 + lane) * 8]);
        async16(Bw + bbase + (size_t)((t + 1) * 8 + c) * 512,
                &Bsl[nxt][(size_t)(c * 64 + lane) * 8]);
      }
      asm volatile("s_waitcnt vmcnt(4)" ::: "memory");
    } else {
      asm volatile("s_waitcnt vmcnt(0)" ::: "memory");
    }
    __builtin_amdgcn_s_barrier();
#pragma unroll
    for (int tt = 0; tt < 2; ++tt) {
      int cc = tt * 4 + q;
      short8 af[2], bf[2];
#pragma unroll
      for (int mi = 0; mi < 2; ++mi)
        af[mi] = *(short8*)&Asl[cur][(size_t)(cc*64 + wm + mi*16 + l15) * 8];
#pragma unroll
      for (int ni = 0; ni < 2; ++ni)
        bf[ni] = *(short8*)&Bsl[cur][(size_t)(cc*64 + wn + ni*16 + l15) * 8];
#pragma unroll
      for (int mi = 0; mi < 2; ++mi)
#pragma unroll
        for (int ni = 0; ni < 2; ++ni)
          acc[mi][ni] = __builtin_amdgcn_mfma_f32_16x16x32_bf16(
              af[mi], bf[ni], acc[mi][ni], 0, 0, 0);
    }
    __builtin_amdgcn_s_barrier();
  }

#pragma unroll
  for (int mi = 0; mi < 2; ++mi) {
#pragma unroll
    for (int ni = 0; ni < 2; ++ni) {
      int col = col0 + wn + ni*16 + l15;
#pragma unroll
      for (int r = 0; r < 4; ++r) {
        int row = row0 + wm + mi*16 + q*4 + r;
        if (row < Mrows) {
          float v = acc[mi][ni][r];
          if (MODE == 0) {
            Cf[(size_t)row*N + col] = v + bias[col];
          } else {
            Cb[pidx(row, col, 32)] = f2bf(gelu_exact(v + bias[col]));
          }
        }
      }
    }
  }
}

// ---------------------------------------------------------------------------
// fused_row<KK,EPI>: block owns 16 rows x 512 cols, K=KK. Packed A and B.
// A-stripe staged to LDS in <=1024-wide K chunks; B streamed from L2 with
// 2-deep register prefetch (4x256B segments per load instr).
// EPI 0: v+bias+residual(xs) -> LN(g,bb) -> xs (linear), xsb (packed)
// EPI 1: cols<256: u_pot -> outu ; cols>=256: h + closed-form proj -> outh
// ---------------------------------------------------------------------------
template<int KK, int EPI>
__global__ __launch_bounds__(256) void fused_row(
    const u16* __restrict__ A, const u16* __restrict__ Bw,
    const float* __restrict__ bias,
    float* __restrict__ xs, u16* __restrict__ xsb,
    const float* __restrict__ g, const float* __restrict__ bb,
    const float* __restrict__ bias2,
    const float* __restrict__ marg, const float* __restrict__ xg,
    float* __restrict__ outu, float* __restrict__ outh)
{
  constexpr int KB  = KK >> 6;
  constexpr int KC  = (KK < 1024) ? KK : 1024;   // K-chunk staged in LDS
  constexpr int NCH = KK / KC;
  __shared__ u16 Alds[16 * KC];                  // <= 32 KB
  __shared__ float red[4][16];
  __shared__ float red2[4][16];
  const int tid = threadIdx.x, lane = tid & 63, wave = tid >> 6;
  const int l15 = lane & 15, q = lane >> 4;
  const int r0 = blockIdx.x * 16;
  const int rb = r0 >> 6, ro = r0 & 63;
  const int gc0 = wave * 128;

  f32x4 acc[8];
#pragma unroll
  for (int i = 0; i < 8; ++i) acc[i] = (f32x4){0,0,0,0};

  for (int ch = 0; ch < NCH; ++ch) {
    const int kc = ch * KC;
    __syncthreads();                 // Alds reuse guard
    // ---- stage A chunk from packed layout: 4x256B segments per instr ----
    for (int idx = tid; idx < 2 * KC; idx += 256) {
      int rloc = idx & 15, cg = idx >> 4;        // cg in [0, KC/8)
      int kbg = (kc >> 6) + (cg >> 3), cc = cg & 7;
      async16(A + ((size_t)(rb * KB + kbg) * 8 + cc) * 512 + (ro + rloc) * 8,
              &Alds[(size_t)idx * 8]);
    }
    asm volatile("s_waitcnt vmcnt(0)" ::: "memory");
    __syncthreads();

    constexpr int S = KC / 32;
    short8 bcur[8], bnxt[8];
    {
      int kk = kc + q * 8;
      int kbg = kk >> 6, cc = (kk & 63) >> 3;
#pragma unroll
      for (int i = 0; i < 8; ++i) {
        int nb = (gc0 >> 6) + (i >> 2), nn = (i & 3) * 16 + l15;
        bcur[i] = *(const short8*)&Bw[((size_t)(nb * KB + kbg) * 8 + cc) * 512
                                      + nn * 8];
      }
    }
    for (int s = 0; s < S; ++s) {
      if (s + 1 < S) {
        int kk = kc + (s + 1) * 32 + q * 8;
        int kbg = kk >> 6, cc = (kk & 63) >> 3;
#pragma unroll
        for (int i = 0; i < 8; ++i) {
          int nb = (gc0 >> 6) + (i >> 2), nn = (i & 3) * 16 + l15;
          bnxt[i] = *(const short8*)&Bw[((size_t)(nb * KB + kbg) * 8 + cc) * 512
                                        + nn * 8];
        }
      }
      short8 af = *(const short8*)&Alds[(size_t)((s * 4 + q) * 16 + l15) * 8];
#pragma unroll
      for (int i = 0; i < 8; ++i)
        acc[i] = __builtin_amdgcn_mfma_f32_16x16x32_bf16(af, bcur[i], acc[i], 0, 0, 0);
#pragma unroll
      for (int i = 0; i < 8; ++i) bcur[i] = bnxt[i];
    }
  }

  // lane's elements: row = q*4+r (local), col = gc0 + i*16 + l15
  if (EPI == 0) {
    float vv[8][4];
#pragma unroll
    for (int i = 0; i < 8; ++i) {
      int col = gc0 + i*16 + l15;
      float bcol = bias[col];
#pragma unroll
      for (int r = 0; r < 4; ++r) {
        int gr = r0 + q*4 + r;
        vv[i][r] = acc[i][r] + bcol + xs[(size_t)gr * Dm + col];
      }
    }
    float ps[4];
#pragma unroll
    for (int r = 0; r < 4; ++r) {
      float s = 0.f;
#pragma unroll
      for (int i = 0; i < 8; ++i) s += vv[i][r];
      ps[r] = s;
    }
#pragma unroll
    for (int o = 1; o < 16; o <<= 1)
#pragma unroll
      for (int r = 0; r < 4; ++r) ps[r] += __shfl_xor(ps[r], o, 64);
    if (l15 == 0)
#pragma unroll
      for (int r = 0; r < 4; ++r) red[wave][q*4 + r] = ps[r];
    __syncthreads();
    float mu[4];
#pragma unroll
    for (int r = 0; r < 4; ++r) {
      int rr = q*4 + r;
      mu[r] = (red[0][rr] + red[1][rr] + red[2][rr] + red[3][rr]) * (1.0f/512.0f);
    }
    float ps2[4];
#pragma unroll
    for (int r = 0; r < 4; ++r) {
      float s = 0.f;
#pragma unroll
      for (int i = 0; i < 8; ++i) { float d = vv[i][r] - mu[r]; s += d * d; }
      ps2[r] = s;
    }
#pragma unroll
    for (int o = 1; o < 16; o <<= 1)
#pragma unroll
      for (int r = 0; r < 4; ++r) ps2[r] += __shfl_xor(ps2[r], o, 64);
    if (l15 == 0)
#pragma unroll
      for (int r = 0; r < 4; ++r) red2[wave][q*4 + r] = ps2[r];
    __syncthreads();
    float inv[4];
#pragma unroll
    for (int r = 0; r < 4; ++r) {
      int rr = q*4 + r;
      inv[r] = rsqrtf((red2[0][rr] + red2[1][rr] + red2[2][rr] + red2[3][rr])
                      * (1.0f/512.0f) + 1e-5f);
    }
#pragma unroll
    for (int i = 0; i < 8; ++i) {
      int col = gc0 + i*16 + l15;
      float gc = g[col], bc = bb[col];
#pragma unroll
      for (int r = 0; r < 4; ++r) {
        int gr = r0 + q*4 + r;
        float y = (vv[i][r] - mu[r]) * inv[r] * gc + bc;
        xs[(size_t)gr * Dm + col] = y;
        xsb[pidx(gr, col, 8)] = f2bf(y);
      }
    }
  } else {
    // EPI 1: u/h head + projection. Waves 2/3 reduce, one uniform barrier,
    // then both groups write.
    float va[8][4];
    if (wave >= 2) {
      float wd[4] = {0.f,0.f,0.f,0.f}, ms[4] = {0.f,0.f,0.f,0.f};
#pragma unroll
      for (int i = 0; i < 8; ++i) {
        int hcol = (gc0 - 256) + i*16 + l15;
        float bcol = bias2[hcol];
        float xv = xg[hcol];
#pragma unroll
        for (int r = 0; r < 4; ++r) {
          int gr = r0 + q*4 + r;
          float a = acc[i][r] + bcol;
          va[i][r] = a;
          float uvm = marg[(size_t)gr * MG + hcol];
          wd[r] += uvm * (f_closed(a) - xv);
          ms[r] += uvm;
        }
      }
#pragma unroll
      for (int o = 1; o < 16; o <<= 1)
#pragma unroll
        for (int r = 0; r < 4; ++r) {
          wd[r] += __shfl_xor(wd[r], o, 64);
          ms[r] += __shfl_xor(ms[r], o, 64);
        }
      if (l15 == 0)
#pragma unroll
        for (int r = 0; r < 4; ++r) {
          red[wave][q*4 + r]  = wd[r];
          red2[wave][q*4 + r] = ms[r];
        }
    }
    __syncthreads();
    if (wave < 2) {
#pragma unroll
      for (int i = 0; i < 8; ++i) {
        int col = gc0 + i*16 + l15;
        float bcol = bias[col];
#pragma unroll
        for (int r = 0; r < 4; ++r) {
          int gr = r0 + q*4 + r;
          outu[(size_t)gr * MG + col] = acc[i][r] + bcol;
        }
      }
    } else {
#pragma unroll
      for (int i = 0; i < 8; ++i) {
        int hcol = (gc0 - 256) + i*16 + l15;
#pragma unroll
        for (int r = 0; r < 4; ++r) {
          int rr = q*4 + r;
          int gr = r0 + rr;
          int b = gr / NP1, n = gr - b * NP1;
          if (n < 64) {
            float corr = (red[2][rr] + red[3][rr])
                       / (red2[2][rr] + red2[3][rr] + 1e-8f);
            outh[(size_t)(b * 64 + n) * MG + hcol] = va[i][r] - corr;
          }
        }
      }
    }
  }
}

// ---------------------------------------------------------------------------
// Attention: one block per (b,h); fp32 in LDS; writes obuf bf16 PACKED (KB=8)
// ---------------------------------------------------------------------------
__global__ __launch_bounds__(256) void attn_kernel(
    const float* __restrict__ qkv, u16* __restrict__ obufb)
{
  __shared__ float qv[65][67];
  __shared__ float ks[65][67];
  __shared__ float ss[65][67];
  const int b = blockIdx.x >> 3, h = blockIdx.x & 7;
  const int tid = threadIdx.x;
  const float* base = qkv + (size_t)b * NP1 * 1536 + h * 64;
  for (int idx = tid; idx < NP1 * 16; idx += 256) {
    int t = idx >> 4, c = (idx & 15) << 2;
    const float* p = base + (size_t)t * 1536 + c;
    float4 q4 = *(const float4*)(p);
    float4 k4 = *(const float4*)(p + 512);
    qv[t][c] = q4.x; qv[t][c+1] = q4.y; qv[t][c+2] = q4.z; qv[t][c+3] = q4.w;
    ks[t][c] = k4.x; ks[t][c+1] = k4.y; ks[t][c+2] = k4.z; ks[t][c+3] = k4.w;
  }
  __syncthreads();
#pragma unroll
  for (int it = 0; it < 2; ++it) {
    int tile = it * 256 + tid;
    if (tile < 289) {
      int ti = (tile / 17) * 4, tj = (tile % 17) * 4;
      const float* qr[4]; const float* kr[4];
#pragma unroll
      for (int i = 0; i < 4; ++i) { qr[i] = qv[min(ti + i, 64)]; kr[i] = ks[min(tj + i, 64)]; }
      float acc[4][4] = {};
      for (int d = 0; d < 64; ++d) {
        float a[4], bvv[4];
#pragma unroll
        for (int i = 0; i < 4; ++i) { a[i] = qr[i][d]; bvv[i] = kr[i][d]; }
#pragma unroll
        for (int i = 0; i < 4; ++i)
#pragma unroll
          for (int j = 0; j < 4; ++j) acc[i][j] += a[i] * bvv[j];
      }
#pragma unroll
      for (int i = 0; i < 4; ++i)
        if (ti + i < 65)
#pragma unroll
          for (int j = 0; j < 4; ++j)
            if (tj + j < 65) ss[ti + i][tj + j] = acc[i][j] * 0.125f;
    }
  }
  __syncthreads();
  for (int idx = tid; idx < NP1 * 16; idx += 256) {
    int t = idx >> 4, c = (idx & 15) << 2;
    float4 v4 = *(const float4*)(base + (size_t)t * 1536 + 1024 + c);
    qv[t][c] = v4.x; qv[t][c+1] = v4.y; qv[t][c+2] = v4.z; qv[t][c+3] = v4.w;
  }
  if (tid < 65) {
    float mx = -1e30f;
    for (int j = 0; j < 65; ++j) mx = fmaxf(mx, ss[tid][j]);
    float s = 0.0f;
    for (int j = 0; j < 65; ++j) { float e = expf(ss[tid][j] - mx); ss[tid][j] = e; s += e; }
    float inv = 1.0f / s;
    for (int j = 0; j < 65; ++j) ss[tid][j] *= inv;
  }
  __syncthreads();
#pragma unroll
  for (int it = 0; it < 2; ++it) {
    int tile = it * 256 + tid;
    if (tile < 272) {
      int ti = (tile >> 4) * 4, d0 = (tile & 15) * 4;
      const float* sr[4];
#pragma unroll
      for (int i = 0; i < 4; ++i) sr[i] = ss[min(ti + i, 64)];
      float acc[4][4] = {};
      for (int j = 0; j < 65; ++j) {
        float v0 = qv[j][d0], v1 = qv[j][d0+1], v2 = qv[j][d0+2], v3 = qv[j][d0+3];
#pragma unroll
        for (int i = 0; i < 4; ++i) {
          float s = sr[i][j];
          acc[i][0] += s * v0; acc[i][1] += s * v1;
          acc[i][2] += s * v2; acc[i][3] += s * v3;
        }
      }
#pragma unroll
      for (int i = 0; i < 4; ++i)
        if (ti + i < 65) {
          ushort4 o;
          o.x = f2bf(acc[i][0]); o.y = f2bf(acc[i][1]);
          o.z = f2bf(acc[i][2]); o.w = f2bf(acc[i][3]);
          *(ushort4*)(obufb + pidx(b * NP1 + ti + i, h * 64 + d0, 8)) = o;
        }
    }
  }
}

// ---------------------------------------------------------------------------
extern "C" void kernel_launch(void* const* d_in, const int* in_sizes, int n_in,
                              void* d_out, int out_size, void* d_ws, size_t ws_size,
                              hipStream_t stream)
{
  const float* marg   = (const float*)d_in[0];
  const float* xg     = (const float*)d_in[1];
  const float* conv_w = (const float*)d_in[2];
  const float* conv_b = (const float*)d_in[3];
  const float* fc_w   = (const float*)d_in[4];
  const float* fc_b   = (const float*)d_in[5];
  const float* ln0_g  = (const float*)d_in[6];
  const float* ln0_b  = (const float*)d_in[7];
  const float* pos    = (const float*)d_in[8];
  const float* qkv_w  = (const float*)d_in[9];
  const float* qkv_b  = (const float*)d_in[10];
  const float* out_w  = (const float*)d_in[11];
  const float* out_b  = (const float*)d_in[12];
  const float* ln1_g  = (const float*)d_in[13];
  const float* ln1_b  = (const float*)d_in[14];
  const float* ff1_w  = (const float*)d_in[15];
  const float* ff1_b  = (const float*)d_in[16];
  const float* ff2_w  = (const float*)d_in[17];
  const float* ff2_b  = (const float*)d_in[18];
  const float* ln2_g  = (const float*)d_in[19];
  const float* ln2_b  = (const float*)d_in[20];
  const float* u_w    = (const float*)d_in[21];
  const float* u_b    = (const float*)d_in[22];
  const float* h_w    = (const float*)d_in[23];
  const float* h_b    = (const float*)d_in[24];
  float* out = (float*)d_out;

  float* ws = (float*)d_ws;
  // packed activation buffers are padded to 1088 rows (17 x 64-row tiles)
  float* xs      = ws;                              // 532480 f32 (linear)
  float* qkvbuf  = ws + 532480;                     // 1597440 f32 (linear)
  u16*   xsb     = (u16*)(ws + 2129920);            // 1088x512 packed
  u16*   obufb   = (u16*)(ws + 2408448);            // 1088x512 packed
  u16*   ffb     = (u16*)(ws + 2686976);            // 1088x2048 packed
  u16*   wbf     = (u16*)(ws + 3801088);            // 9699328 u16 packed

  const u16* qkv_bw = wbf;
  const u16* out_bw = wbf + 2359296;
  const u16* ff1_bw = wbf + 3145728;
  const u16* ff2_bw = wbf + 6291456;
  const u16* uh_bw  = wbf + 9437184;   // u rows 0..255, h rows 256..511

  prep_kernel<<<772, 256, 0, stream>>>(
      qkv_w, out_w, ff1_w, ff2_w, u_w, h_w, wbf,
      marg, conv_w, conv_b, fc_w, fc_b, ln0_g, ln0_b, pos, xs, xsb);

  for (int l = 0; l < 3; ++l) {
    gemm_mfma<0><<<dim3(24, 17), 256, 0, stream>>>(
        xsb, qkv_bw + (size_t)l*786432, qkv_b + l*1536, qkvbuf,
        nullptr, BT, 1536, 512);
    attn_kernel<<<128, 256, 0, stream>>>(qkvbuf, obufb);
    fused_row<512, 0><<<65, 256, 0, stream>>>(
        obufb, out_bw + (size_t)l*262144, out_b + l*512,
        xs, xsb, ln1_g + l*512, ln1_b + l*512,
        nullptr, nullptr, nullptr, nullptr, nullptr);
    gemm_mfma<1><<<dim3(32, 17), 256, 0, stream>>>(
        xsb, ff1_bw + (size_t)l*1048576, ff1_b + l*2048, nullptr,
        ffb, BT, 2048, 512);
    fused_row<2048, 0><<<65, 256, 0, stream>>>(
        ffb, ff2_bw + (size_t)l*1048576, ff2_b + l*512,
        xs, xsb, ln2_g + l*512, ln2_b + l*512,
        nullptr, nullptr, nullptr, nullptr, nullptr);
  }

  fused_row<512, 1><<<65, 256, 0, stream>>>(
      xsb, uh_bw, u_b,
      nullptr, nullptr, nullptr, nullptr,
      h_b, marg, xg, out, out + 1040*256);
}

// Round 7
// 379.268 us; speedup vs baseline: 2.8274x; 1.1089x over previous
//
#include <hip/hip_runtime.h>
#include <math.h>

// ---------------------------------------------------------------------------
// B=16, NP1=65, BT=1040, Mg=256, D=512, H=8, DH=64, L=3, DFF=2048
// R15: R14 resubmit with launch-hazard fixes (R3 precedent: "container failed
// twice" = kernel-side launch/compile fault). Changes vs R14:
//  - fused_qkv_attn: __shared__ union replaced by flat alignas(16) u16 buffer
//    + pointer casts (R10-proven aliasing pattern for global_load_lds dest)
//  - alignas(16) on all LDS arrays accessed 16B-wide
// Graph unchanged: 14 dispatches.
//  - fused_qkv_attn: one block per (b,h), MFMA Q,K,V from packed xsb/qkv_w,
//    attn phases in-block (Q,K fp32 LDS; V bf16 LDS)
//  - fused_row 8-wave (512 thr): wave owns 64 cols; packed A (LDS) + B (L2,
//    2-deep reg prefetch); LN / u-h-proj epilogues
// ---------------------------------------------------------------------------

#define BT   1040
#define NP1  65
#define Dm   512
#define MG   256

typedef short short8 __attribute__((ext_vector_type(8)));
typedef float f32x4  __attribute__((ext_vector_type(4)));
typedef unsigned short u16;

// packed u16 index of element (r, c) in a [R][C] bf16 matrix, KB = C/64
__device__ __forceinline__ size_t pidx(int r, int c, int KB) {
  return ((size_t)((r >> 6) * KB + (c >> 6)) * 8 + ((c & 63) >> 3)) * 512
       + (size_t)((r & 63) * 8 + (c & 7));
}

__device__ __forceinline__ u16 f2bf(float f) {
  unsigned int u = __float_as_uint(f);
  u += 0x7FFF + ((u >> 16) & 1);          // RNE
  return (u16)(u >> 16);
}

__device__ __forceinline__ float bf2f(u16 v) {
  return __uint_as_float((unsigned int)v << 16);
}

__device__ __forceinline__ float gelu_exact(float x) {
  return 0.5f * x * (1.0f + erff(x * 0.70710678118654752f));
}

__device__ __forceinline__ void async16(const u16* g, u16* l) {
  __builtin_amdgcn_global_load_lds(
      (const __attribute__((address_space(1))) unsigned int*)g,
      (__attribute__((address_space(3))) unsigned int*)l, 16, 0, 0);
}

__device__ __forceinline__ float wred(float v) {
#pragma unroll
  for (int o = 32; o; o >>= 1) v += __shfl_xor(v, o, 64);
  return v;
}

__device__ __forceinline__ float block_reduce_sum(float v, float* s) {
#pragma unroll
  for (int off = 32; off; off >>= 1) v += __shfl_down(v, off, 64);
  int lane = threadIdx.x & 63, wid = threadIdx.x >> 6;
  __syncthreads();
  if (lane == 0) s[wid] = v;
  __syncthreads();
  return s[0] + s[1] + s[2] + s[3];
}

// closed-form expected grid value under weights exp(-a*x_j/eps), x_j uniform:
__device__ __forceinline__ float f_closed(float a) {
  const float tf = 2.3529411765f;     // (6/255)*100
  float t = a * tf;
  float s = fabsf(t);
  float E;
  if (s < 1e-4f) {
    E = 127.5f - 5461.25f * t;        // series; kappa2=(256^2-1)/12
  } else {
    float u = s * 256.0f;
    float term2 = (u < 80.0f) ? 256.0f / expm1f(u) : 0.0f;
    float Epos = 1.0f / expm1f(s) - term2;
    E = (t > 0.0f) ? Epos : 255.0f - Epos;
  }
  return -3.0f + 0.0235294118f * E;   // delta = 6/255
}

// ---------------------------------------------------------------------------
// prep: blocks [0,512) convert+PACK weights fp32->bf16; [512,772) embed
// ---------------------------------------------------------------------------
__global__ __launch_bounds__(256) void prep_kernel(
    const float* __restrict__ qkv_w, const float* __restrict__ out_w,
    const float* __restrict__ ff1_w, const float* __restrict__ ff2_w,
    const float* __restrict__ u_w,   const float* __restrict__ h_w,
    u16* __restrict__ wdst,
    const float* __restrict__ marg, const float* __restrict__ conv_w,
    const float* __restrict__ conv_b, const float* __restrict__ fc_w,
    const float* __restrict__ fc_b, const float* __restrict__ g,
    const float* __restrict__ bb, const float* __restrict__ pos,
    float* __restrict__ xs, u16* __restrict__ xsb)
{
  const int tid = threadIdx.x;
  if (blockIdx.x < 512) {
    const size_t O1 = 2359296, O2 = 3145728, O3 = 6291456;
    const size_t O4 = 9437184, O5 = 9568256, TOT4 = 9699328 / 4;
    for (size_t e4 = (size_t)blockIdx.x * 256 + tid; e4 < TOT4;
         e4 += (size_t)512 * 256) {
      size_t e = e4 * 4;
      const float* src; size_t base; int n, k, KB;
      if (e < O1)      { size_t r = e;      src = qkv_w + r; base = 0;
                         n = (int)(r >> 9);  k = (int)(r & 511);  KB = 8; }
      else if (e < O2) { size_t r = e - O1; src = out_w + r; base = O1;
                         n = (int)(r >> 9);  k = (int)(r & 511);  KB = 8; }
      else if (e < O3) { size_t r = e - O2; src = ff1_w + r; base = O2;
                         n = (int)(r >> 9);  k = (int)(r & 511);  KB = 8; }
      else if (e < O4) { size_t r = e - O3; src = ff2_w + r; base = O3;
                         n = (int)(r >> 11); k = (int)(r & 2047); KB = 32; }
      else if (e < O5) { size_t r = e - O4; src = u_w + r;   base = O4;
                         n = (int)(r >> 9);  k = (int)(r & 511);  KB = 8; }
      else             { size_t r = e - O5; src = h_w + r;   base = O4;
                         n = 256 + (int)(r >> 9); k = (int)(r & 511); KB = 8; }
      float4 v = *(const float4*)src;
      unsigned int lo = (unsigned int)f2bf(v.x) | ((unsigned int)f2bf(v.y) << 16);
      unsigned int hi = (unsigned int)f2bf(v.z) | ((unsigned int)f2bf(v.w) << 16);
      *(uint2*)(wdst + base + pidx(n, k, KB)) = make_uint2(lo, hi);
    }
    return;
  }
  // ---- embed: 4 tokens per block ----
  __shared__ float es[4][128];
  __shared__ float sS[4];
  __shared__ float edge[4][4];
  __shared__ float red[4];
  const int t0 = (blockIdx.x - 512) * 4;
  const int lane = tid & 63, wave = tid >> 6;
  {
    float4 mv = *(const float4*)(marg + (size_t)(t0 + wave) * MG + lane * 4);
    float S = wred(mv.x + mv.y + mv.z + mv.w);
    if (lane == 0) sS[wave] = S;
  }
  if (tid < 16) {
    int k = tid >> 2, e = tid & 3;
    int idx = (e < 2) ? e : (e + 252);       // 0,1,254,255
    edge[k][e] = marg[(size_t)(t0 + k) * MG + idx];
  }
  __syncthreads();
  if (tid < 128) {
    int o = tid;
    float w0 = conv_w[o*5+0], w1 = conv_w[o*5+1], w2 = conv_w[o*5+2];
    float w3 = conv_w[o*5+3], w4 = conv_w[o*5+4], cb = conv_b[o];
#pragma unroll
    for (int k = 0; k < 4; ++k) {
      float S = sS[k];
      float x0 = edge[k][0], x1 = edge[k][1], x254 = edge[k][2], x255 = edge[k][3];
      es[k][o] = (w0*(S - x254 - x255) + w1*(S - x255) + w2*S
                + w3*(S - x0) + w4*(S - x0 - x1)) * (1.0f/256.0f) + cb;
    }
  }
  __syncthreads();
  float b0 = fc_b[tid], b1 = fc_b[tid + 256];
  float z[4][2];
#pragma unroll
  for (int k = 0; k < 4; ++k) { z[k][0] = b0; z[k][1] = b1; }
#pragma unroll 4
  for (int o = 0; o < 128; ++o) {
    float f0 = fc_w[(size_t)o*Dm + tid];
    float f1 = fc_w[(size_t)o*Dm + tid + 256];
#pragma unroll
    for (int k = 0; k < 4; ++k) {
      float e = es[k][o];
      z[k][0] += e * f0; z[k][1] += e * f1;
    }
  }
  float g0 = g[tid], g1 = g[tid+256], e0 = bb[tid], e1 = bb[tid+256];
#pragma unroll
  for (int k = 0; k < 4; ++k) {
    float mu = block_reduce_sum(z[k][0] + z[k][1], red) * (1.0f/512.0f);
    float d0 = z[k][0] - mu, d1 = z[k][1] - mu;
    float var = block_reduce_sum(d0*d0 + d1*d1, red) * (1.0f/512.0f);
    float inv = rsqrtf(var + 1e-5f);
    int t = t0 + k, p = t % NP1;
    float y0 = gelu_exact(d0*inv*g0 + e0) + pos[(size_t)p*Dm + tid];
    float y1 = gelu_exact(d1*inv*g1 + e1) + pos[(size_t)p*Dm + tid + 256];
    xs[(size_t)t*Dm + tid]        = y0;
    xs[(size_t)t*Dm + tid + 256]  = y1;
    xsb[pidx(t, tid, 8)]          = f2bf(y0);
    xsb[pidx(t, tid + 256, 8)]    = f2bf(y1);
  }
}

// ---------------------------------------------------------------------------
// 64x64 MFMA tile GEMM (ff1 only), packed A/B, async16 dbuf, 4 waves 2x2.
// MODE 1: bf16 gelu(v+bias) -> PACKED Cb (KB=32)
// ---------------------------------------------------------------------------
template<int MODE>
__global__ __launch_bounds__(256) void gemm_mfma(
    const u16* __restrict__ A, const u16* __restrict__ Bw,
    const float* __restrict__ bias, float* __restrict__ Cf,
    u16* __restrict__ Cb, int Mrows, int N, int K)
{
  __shared__ alignas(16) u16 Asl[2][4096];
  __shared__ alignas(16) u16 Bsl[2][4096];
  const int tid = threadIdx.x;
  const int row0 = blockIdx.y * 64, col0 = blockIdx.x * 64;
  const int lane = tid & 63, wave = tid >> 6;
  const int wm = (wave >> 1) * 32, wn = (wave & 1) * 32;
  const int l15 = lane & 15, q = lane >> 4;
  const int KB = K >> 6;

  f32x4 acc[2][2];
  acc[0][0] = (f32x4){0,0,0,0}; acc[0][1] = (f32x4){0,0,0,0};
  acc[1][0] = (f32x4){0,0,0,0}; acc[1][1] = (f32x4){0,0,0,0};

  const size_t abase = (size_t)blockIdx.y * KB * 4096 + (size_t)lane * 8;
  const size_t bbase = (size_t)blockIdx.x * KB * 4096 + (size_t)lane * 8;
  const int c0w = wave * 2;

#pragma unroll
  for (int i = 0; i < 2; ++i) {
    int c = c0w + i;
    async16(A + abase + (size_t)c * 512, &Asl[0][(size_t)(c * 64 + lane) * 8]);
    async16(Bw + bbase + (size_t)c * 512, &Bsl[0][(size_t)(c * 64 + lane) * 8]);
  }

  const int nk = K >> 6;
  for (int t = 0; t < nk; ++t) {
    const int cur = t & 1;
    if (t + 1 < nk) {
      const int nxt = cur ^ 1;
#pragma unroll
      for (int i = 0; i < 2; ++i) {
        int c = c0w + i;
        async16(A + abase + (size_t)((t + 1) * 8 + c) * 512,
                &Asl[nxt][(size_t)(c * 64 + lane) * 8]);
        async16(Bw + bbase + (size_t)((t + 1) * 8 + c) * 512,
                &Bsl[nxt][(size_t)(c * 64 + lane) * 8]);
      }
      asm volatile("s_waitcnt vmcnt(4)" ::: "memory");
    } else {
      asm volatile("s_waitcnt vmcnt(0)" ::: "memory");
    }
    __builtin_amdgcn_s_barrier();
#pragma unroll
    for (int tt = 0; tt < 2; ++tt) {
      int cc = tt * 4 + q;
      short8 af[2], bf[2];
#pragma unroll
      for (int mi = 0; mi < 2; ++mi)
        af[mi] = *(short8*)&Asl[cur][(size_t)(cc*64 + wm + mi*16 + l15) * 8];
#pragma unroll
      for (int ni = 0; ni < 2; ++ni)
        bf[ni] = *(short8*)&Bsl[cur][(size_t)(cc*64 + wn + ni*16 + l15) * 8];
#pragma unroll
      for (int mi = 0; mi < 2; ++mi)
#pragma unroll
        for (int ni = 0; ni < 2; ++ni)
          acc[mi][ni] = __builtin_amdgcn_mfma_f32_16x16x32_bf16(
              af[mi], bf[ni], acc[mi][ni], 0, 0, 0);
    }
    __builtin_amdgcn_s_barrier();
  }

#pragma unroll
  for (int mi = 0; mi < 2; ++mi) {
#pragma unroll
    for (int ni = 0; ni < 2; ++ni) {
      int col = col0 + wn + ni*16 + l15;
#pragma unroll
      for (int r = 0; r < 4; ++r) {
        int row = row0 + wm + mi*16 + q*4 + r;
        if (row < Mrows) {
          float v = acc[mi][ni][r];
          if (MODE == 0) {
            Cf[(size_t)row*N + col] = v + bias[col];
          } else {
            Cb[pidx(row, col, 32)] = f2bf(gelu_exact(v + bias[col]));
          }
        }
      }
    }
  }
}

// ---------------------------------------------------------------------------
// fused_qkv_attn: one block per (b,h). MFMA computes Q,K,V (65x192, K=512)
// from packed xsb / qkv_w (accumulation order identical to old gemm).
// Q,K fp32 LDS; V bf16 LDS; scores alias the A-stage buffer (flat u16 buf +
// casts, R10-proven pattern). obufb packed.
// ---------------------------------------------------------------------------
__global__ __launch_bounds__(256) void fused_qkv_attn(
    const u16* __restrict__ xsb, const u16* __restrict__ qkvw,
    const float* __restrict__ qkvb, u16* __restrict__ obufb)
{
  __shared__ alignas(16) u16 stbuf[10240];       // 20480 B: A-stage | scores
  __shared__ alignas(16) float qf[65][67];
  __shared__ alignas(16) float kf[65][67];
  __shared__ alignas(16) u16   vb[65][68];
  u16* sta = stbuf;                              // [kg 16][row 80][8]
  float (*ss)[67] = (float (*)[67])stbuf;        // [65][67] = 17420 B, fits

  const int b = blockIdx.x >> 3, h = blockIdx.x & 7;
  const int tid = threadIdx.x, lane = tid & 63, wave = tid >> 6;
  const int l15 = lane & 15, q = lane >> 4;
  const int rowg0 = b * NP1;

  f32x4 acc[5][3];
#pragma unroll
  for (int rt = 0; rt < 5; ++rt)
#pragma unroll
    for (int j = 0; j < 3; ++j) acc[rt][j] = (f32x4){0,0,0,0};

  // ---- GEMM: K=512 in 4 chunks of 128 ----
  for (int ch = 0; ch < 4; ++ch) {
    __syncthreads();
    for (int idx = tid; idx < 16 * 80; idx += 256) {
      int kg = idx / 80, rl = idx - kg * 80;
      int r = rowg0 + min(rl, 64);
      async16(xsb + pidx(r, ch * 128 + kg * 8, 8), &sta[(size_t)idx * 8]);
    }
    asm volatile("s_waitcnt vmcnt(0)" ::: "memory");
    __syncthreads();

    short8 bcur[3], bnxt[3];
#pragma unroll
    for (int j = 0; j < 3; ++j) {
      int f = wave * 3 + j, region = f >> 2, sub = f & 3;
      int nb = region * 8 + h, nn = sub * 16 + l15;
      int kk = ch * 128 + q * 8;
      int kbg = kk >> 6, cc = (kk & 63) >> 3;
      bcur[j] = *(const short8*)&qkvw[((size_t)(nb * 8 + kbg) * 8 + cc) * 512
                                      + nn * 8];
    }
#pragma unroll
    for (int s = 0; s < 4; ++s) {
      if (s + 1 < 4) {
#pragma unroll
        for (int j = 0; j < 3; ++j) {
          int f = wave * 3 + j, region = f >> 2, sub = f & 3;
          int nb = region * 8 + h, nn = sub * 16 + l15;
          int kk = ch * 128 + (s + 1) * 32 + q * 8;
          int kbg = kk >> 6, cc = (kk & 63) >> 3;
          bnxt[j] = *(const short8*)&qkvw[((size_t)(nb * 8 + kbg) * 8 + cc) * 512
                                          + nn * 8];
        }
      }
      short8 af[5];
#pragma unroll
      for (int rt = 0; rt < 5; ++rt)
        af[rt] = *(short8*)&sta[(size_t)((s * 4 + q) * 80 + rt * 16 + l15) * 8];
#pragma unroll
      for (int rt = 0; rt < 5; ++rt)
#pragma unroll
        for (int j = 0; j < 3; ++j)
          acc[rt][j] = __builtin_amdgcn_mfma_f32_16x16x32_bf16(
              af[rt], bcur[j], acc[rt][j], 0, 0, 0);
#pragma unroll
      for (int j = 0; j < 3; ++j) bcur[j] = bnxt[j];
    }
  }

  // ---- write Q,K (fp32) and V (bf16) to LDS ----
#pragma unroll
  for (int rt = 0; rt < 5; ++rt) {
#pragma unroll
    for (int j = 0; j < 3; ++j) {
      int f = wave * 3 + j, region = f >> 2, sub = f & 3;
      int cw = sub * 16 + l15;
      float bias = qkvb[region * 512 + h * 64 + cw];
#pragma unroll
      for (int r = 0; r < 4; ++r) {
        int row = rt * 16 + q * 4 + r;
        if (row < 65) {
          float v = acc[rt][j][r] + bias;
          if      (region == 0) qf[row][cw] = v;
          else if (region == 1) kf[row][cw] = v;
          else                  vb[row][cw] = f2bf(v);
        }
      }
    }
  }
  __syncthreads();

  // ---- QK^T (289 4x4 tiles) ----
#pragma unroll
  for (int it = 0; it < 2; ++it) {
    int tile = it * 256 + tid;
    if (tile < 289) {
      int ti = (tile / 17) * 4, tj = (tile % 17) * 4;
      const float* qr[4]; const float* kr[4];
#pragma unroll
      for (int i = 0; i < 4; ++i) { qr[i] = qf[min(ti + i, 64)]; kr[i] = kf[min(tj + i, 64)]; }
      float a4[4][4] = {};
      for (int d = 0; d < 64; ++d) {
        float a[4], bvv[4];
#pragma unroll
        for (int i = 0; i < 4; ++i) { a[i] = qr[i][d]; bvv[i] = kr[i][d]; }
#pragma unroll
        for (int i = 0; i < 4; ++i)
#pragma unroll
          for (int j = 0; j < 4; ++j) a4[i][j] += a[i] * bvv[j];
      }
#pragma unroll
      for (int i = 0; i < 4; ++i)
        if (ti + i < 65)
#pragma unroll
          for (int j = 0; j < 4; ++j)
            if (tj + j < 65) ss[ti + i][tj + j] = a4[i][j] * 0.125f;
    }
  }
  __syncthreads();

  // ---- softmax rows ----
  if (tid < 65) {
    float mx = -1e30f;
    for (int j = 0; j < 65; ++j) mx = fmaxf(mx, ss[tid][j]);
    float s = 0.0f;
    for (int j = 0; j < 65; ++j) { float e = expf(ss[tid][j] - mx); ss[tid][j] = e; s += e; }
    float inv = 1.0f / s;
    for (int j = 0; j < 65; ++j) ss[tid][j] *= inv;
  }
  __syncthreads();

  // ---- PV (272 4x4 tiles), V from bf16 LDS ----
#pragma unroll
  for (int it = 0; it < 2; ++it) {
    int tile = it * 256 + tid;
    if (tile < 272) {
      int ti = (tile >> 4) * 4, d0 = (tile & 15) * 4;
      const float* sr[4];
#pragma unroll
      for (int i = 0; i < 4; ++i) sr[i] = ss[min(ti + i, 64)];
      float a4[4][4] = {};
      for (int j = 0; j < 65; ++j) {
        float v0 = bf2f(vb[j][d0]),   v1 = bf2f(vb[j][d0+1]);
        float v2 = bf2f(vb[j][d0+2]), v3 = bf2f(vb[j][d0+3]);
#pragma unroll
        for (int i = 0; i < 4; ++i) {
          float s = sr[i][j];
          a4[i][0] += s * v0; a4[i][1] += s * v1;
          a4[i][2] += s * v2; a4[i][3] += s * v3;
        }
      }
#pragma unroll
      for (int i = 0; i < 4; ++i)
        if (ti + i < 65) {
          ushort4 o;
          o.x = f2bf(a4[i][0]); o.y = f2bf(a4[i][1]);
          o.z = f2bf(a4[i][2]); o.w = f2bf(a4[i][3]);
          *(ushort4*)(obufb + pidx(b * NP1 + ti + i, h * 64 + d0, 8)) = o;
        }
    }
  }
}

// ---------------------------------------------------------------------------
// fused_row<KK,EPI>: 8 waves (512 thr), block owns 16 rows x 512 cols, K=KK.
// Each wave owns 64 cols (4 frags). Packed A (LDS-staged) and B (L2-streamed,
// 2-deep register prefetch).
// EPI 0: v+bias+residual(xs) -> LN(g,bb) -> xs (linear), xsb (packed)
// EPI 1: waves 0-3 u_pot -> outu ; waves 4-7 h + closed-form proj -> outh
// ---------------------------------------------------------------------------
template<int KK, int EPI>
__global__ __launch_bounds__(512) void fused_row(
    const u16* __restrict__ A, const u16* __restrict__ Bw,
    const float* __restrict__ bias,
    float* __restrict__ xs, u16* __restrict__ xsb,
    const float* __restrict__ g, const float* __restrict__ bb,
    const float* __restrict__ bias2,
    const float* __restrict__ marg, const float* __restrict__ xg,
    float* __restrict__ outu, float* __restrict__ outh)
{
  constexpr int KB  = KK >> 6;
  constexpr int KC  = (KK < 1024) ? KK : 1024;
  constexpr int NCH = KK / KC;
  __shared__ alignas(16) u16 Alds[16 * KC];      // <= 32 KB
  __shared__ float red[8][16];
  __shared__ float red2[8][16];
  const int tid = threadIdx.x, lane = tid & 63, wave = tid >> 6;
  const int l15 = lane & 15, q = lane >> 4;
  const int r0 = blockIdx.x * 16;
  const int rb = r0 >> 6, ro = r0 & 63;
  const int gc0 = wave * 64;                     // wave's 64 output cols
  const int nb = wave;                           // col block index

  f32x4 acc[4];
#pragma unroll
  for (int i = 0; i < 4; ++i) acc[i] = (f32x4){0,0,0,0};

  for (int ch = 0; ch < NCH; ++ch) {
    const int kc = ch * KC;
    __syncthreads();
    for (int idx = tid; idx < 2 * KC; idx += 512) {
      int rloc = idx & 15, cg = idx >> 4;
      int kbg = (kc >> 6) + (cg >> 3), cc = cg & 7;
      async16(A + ((size_t)(rb * KB + kbg) * 8 + cc) * 512 + (ro + rloc) * 8,
              &Alds[(size_t)idx * 8]);
    }
    asm volatile("s_waitcnt vmcnt(0)" ::: "memory");
    __syncthreads();

    constexpr int S = KC / 32;
    short8 bcur[4], bnxt[4];
    {
      int kk = kc + q * 8;
      int kbg = kk >> 6, cc = (kk & 63) >> 3;
#pragma unroll
      for (int i = 0; i < 4; ++i)
        bcur[i] = *(const short8*)&Bw[((size_t)(nb * KB + kbg) * 8 + cc) * 512
                                      + (i * 16 + l15) * 8];
    }
    for (int s = 0; s < S; ++s) {
      if (s + 1 < S) {
        int kk = kc + (s + 1) * 32 + q * 8;
        int kbg = kk >> 6, cc = (kk & 63) >> 3;
#pragma unroll
        for (int i = 0; i < 4; ++i)
          bnxt[i] = *(const short8*)&Bw[((size_t)(nb * KB + kbg) * 8 + cc) * 512
                                        + (i * 16 + l15) * 8];
      }
      short8 af = *(const short8*)&Alds[(size_t)((s * 4 + q) * 16 + l15) * 8];
#pragma unroll
      for (int i = 0; i < 4; ++i)
        acc[i] = __builtin_amdgcn_mfma_f32_16x16x32_bf16(af, bcur[i], acc[i], 0, 0, 0);
#pragma unroll
      for (int i = 0; i < 4; ++i) bcur[i] = bnxt[i];
    }
  }

  // lane's elements: row = q*4+r (local), col = gc0 + i*16 + l15
  if (EPI == 0) {
    float vv[4][4];
#pragma unroll
    for (int i = 0; i < 4; ++i) {
      int col = gc0 + i*16 + l15;
      float bcol = bias[col];
#pragma unroll
      for (int r = 0; r < 4; ++r) {
        int gr = r0 + q*4 + r;
        vv[i][r] = acc[i][r] + bcol + xs[(size_t)gr * Dm + col];
      }
    }
    float ps[4];
#pragma unroll
    for (int r = 0; r < 4; ++r) {
      float s = 0.f;
#pragma unroll
      for (int i = 0; i < 4; ++i) s += vv[i][r];
      ps[r] = s;
    }
#pragma unroll
    for (int o = 1; o < 16; o <<= 1)
#pragma unroll
      for (int r = 0; r < 4; ++r) ps[r] += __shfl_xor(ps[r], o, 64);
    if (l15 == 0)
#pragma unroll
      for (int r = 0; r < 4; ++r) red[wave][q*4 + r] = ps[r];
    __syncthreads();
    float mu[4];
#pragma unroll
    for (int r = 0; r < 4; ++r) {
      int rr = q*4 + r;
      float s = 0.f;
#pragma unroll
      for (int w = 0; w < 8; ++w) s += red[w][rr];
      mu[r] = s * (1.0f/512.0f);
    }
    float ps2[4];
#pragma unroll
    for (int r = 0; r < 4; ++r) {
      float s = 0.f;
#pragma unroll
      for (int i = 0; i < 4; ++i) { float d = vv[i][r] - mu[r]; s += d * d; }
      ps2[r] = s;
    }
#pragma unroll
    for (int o = 1; o < 16; o <<= 1)
#pragma unroll
      for (int r = 0; r < 4; ++r) ps2[r] += __shfl_xor(ps2[r], o, 64);
    if (l15 == 0)
#pragma unroll
      for (int r = 0; r < 4; ++r) red2[wave][q*4 + r] = ps2[r];
    __syncthreads();
    float inv[4];
#pragma unroll
    for (int r = 0; r < 4; ++r) {
      int rr = q*4 + r;
      float s = 0.f;
#pragma unroll
      for (int w = 0; w < 8; ++w) s += red2[w][rr];
      inv[r] = rsqrtf(s * (1.0f/512.0f) + 1e-5f);
    }
#pragma unroll
    for (int i = 0; i < 4; ++i) {
      int col = gc0 + i*16 + l15;
      float gc = g[col], bc = bb[col];
#pragma unroll
      for (int r = 0; r < 4; ++r) {
        int gr = r0 + q*4 + r;
        float y = (vv[i][r] - mu[r]) * inv[r] * gc + bc;
        xs[(size_t)gr * Dm + col] = y;
        xsb[pidx(gr, col, 8)] = f2bf(y);
      }
    }
  } else {
    // EPI 1: waves 4-7 own h cols; reduce, one uniform barrier, both write.
    float va[4][4];
    if (wave >= 4) {
      float wd[4] = {0.f,0.f,0.f,0.f}, ms[4] = {0.f,0.f,0.f,0.f};
#pragma unroll
      for (int i = 0; i < 4; ++i) {
        int hcol = (gc0 - 256) + i*16 + l15;
        float bcol = bias2[hcol];
        float xv = xg[hcol];
#pragma unroll
        for (int r = 0; r < 4; ++r) {
          int gr = r0 + q*4 + r;
          float a = acc[i][r] + bcol;
          va[i][r] = a;
          float uvm = marg[(size_t)gr * MG + hcol];
          wd[r] += uvm * (f_closed(a) - xv);
          ms[r] += uvm;
        }
      }
#pragma unroll
      for (int o = 1; o < 16; o <<= 1)
#pragma unroll
        for (int r = 0; r < 4; ++r) {
          wd[r] += __shfl_xor(wd[r], o, 64);
          ms[r] += __shfl_xor(ms[r], o, 64);
        }
      if (l15 == 0)
#pragma unroll
        for (int r = 0; r < 4; ++r) {
          red[wave][q*4 + r]  = wd[r];
          red2[wave][q*4 + r] = ms[r];
        }
    }
    __syncthreads();
    if (wave < 4) {
#pragma unroll
      for (int i = 0; i < 4; ++i) {
        int col = gc0 + i*16 + l15;
        float bcol = bias[col];
#pragma unroll
        for (int r = 0; r < 4; ++r) {
          int gr = r0 + q*4 + r;
          outu[(size_t)gr * MG + col] = acc[i][r] + bcol;
        }
      }
    } else {
#pragma unroll
      for (int i = 0; i < 4; ++i) {
        int hcol = (gc0 - 256) + i*16 + l15;
#pragma unroll
        for (int r = 0; r < 4; ++r) {
          int rr = q*4 + r;
          int gr = r0 + rr;
          int bI = gr / NP1, n = gr - bI * NP1;
          if (n < 64) {
            float num = red[4][rr] + red[5][rr] + red[6][rr] + red[7][rr];
            float den = red2[4][rr] + red2[5][rr] + red2[6][rr] + red2[7][rr];
            float corr = num / (den + 1e-8f);
            outh[(size_t)(bI * 64 + n) * MG + hcol] = va[i][r] - corr;
          }
        }
      }
    }
  }
}

// ---------------------------------------------------------------------------
extern "C" void kernel_launch(void* const* d_in, const int* in_sizes, int n_in,
                              void* d_out, int out_size, void* d_ws, size_t ws_size,
                              hipStream_t stream)
{
  const float* marg   = (const float*)d_in[0];
  const float* xg     = (const float*)d_in[1];
  const float* conv_w = (const float*)d_in[2];
  const float* conv_b = (const float*)d_in[3];
  const float* fc_w   = (const float*)d_in[4];
  const float* fc_b   = (const float*)d_in[5];
  const float* ln0_g  = (const float*)d_in[6];
  const float* ln0_b  = (const float*)d_in[7];
  const float* pos    = (const float*)d_in[8];
  const float* qkv_w  = (const float*)d_in[9];
  const float* qkv_b  = (const float*)d_in[10];
  const float* out_w  = (const float*)d_in[11];
  const float* out_b  = (const float*)d_in[12];
  const float* ln1_g  = (const float*)d_in[13];
  const float* ln1_b  = (const float*)d_in[14];
  const float* ff1_w  = (const float*)d_in[15];
  const float* ff1_b  = (const float*)d_in[16];
  const float* ff2_w  = (const float*)d_in[17];
  const float* ff2_b  = (const float*)d_in[18];
  const float* ln2_g  = (const float*)d_in[19];
  const float* ln2_b  = (const float*)d_in[20];
  const float* u_w    = (const float*)d_in[21];
  const float* u_b    = (const float*)d_in[22];
  const float* h_w    = (const float*)d_in[23];
  const float* h_b    = (const float*)d_in[24];
  float* out = (float*)d_out;

  float* ws = (float*)d_ws;
  float* xs      = ws;                              // 532480 f32 (linear)
  u16*   xsb     = (u16*)(ws + 2129920);            // 1088x512 packed
  u16*   obufb   = (u16*)(ws + 2408448);            // 1088x512 packed
  u16*   ffb     = (u16*)(ws + 2686976);            // 1088x2048 packed
  u16*   wbf     = (u16*)(ws + 3801088);            // 9699328 u16 packed

  const u16* qkv_bw = wbf;
  const u16* out_bw = wbf + 2359296;
  const u16* ff1_bw = wbf + 3145728;
  const u16* ff2_bw = wbf + 6291456;
  const u16* uh_bw  = wbf + 9437184;   // u rows 0..255, h rows 256..511

  prep_kernel<<<772, 256, 0, stream>>>(
      qkv_w, out_w, ff1_w, ff2_w, u_w, h_w, wbf,
      marg, conv_w, conv_b, fc_w, fc_b, ln0_g, ln0_b, pos, xs, xsb);

  for (int l = 0; l < 3; ++l) {
    fused_qkv_attn<<<128, 256, 0, stream>>>(
        xsb, qkv_bw + (size_t)l*786432, qkv_b + l*1536, obufb);
    fused_row<512, 0><<<65, 512, 0, stream>>>(
        obufb, out_bw + (size_t)l*262144, out_b + l*512,
        xs, xsb, ln1_g + l*512, ln1_b + l*512,
        nullptr, nullptr, nullptr, nullptr, nullptr);
    gemm_mfma<1><<<dim3(32, 17), 256, 0, stream>>>(
        xsb, ff1_bw + (size_t)l*1048576, ff1_b + l*2048, nullptr,
        ffb, BT, 2048, 512);
    fused_row<2048, 0><<<65, 512, 0, stream>>>(
        ffb, ff2_bw + (size_t)l*1048576, ff2_b + l*512,
        xs, xsb, ln2_g + l*512, ln2_b + l*512,
        nullptr, nullptr, nullptr, nullptr, nullptr);
  }

  fused_row<512, 1><<<65, 512, 0, stream>>>(
      xsb, uh_bw, u_b,
      nullptr, nullptr, nullptr, nullptr,
      h_b, marg, xg, out, out + 1040*256);
}